// Round 6
// baseline (171.755 us; speedup 1.0000x reference)
//
#include <hip/hip_runtime.h>
#include <hip/hip_bf16.h>

// B=2, S=2048, D=1024, H=16, HD=64. fp32 in, fp32 out, bf16-tolerance threshold.
// Pipeline: convert->bf16 | QKV GEMM (mfma, fused bias+RoPE) | V-transpose |
//           flash attn (k-split x2, fused A/B tiles, fixed-max softmax) | combine | out GEMM.

typedef unsigned short u16;
typedef short bf16x8 __attribute__((ext_vector_type(8)));
typedef float f32x4 __attribute__((ext_vector_type(4)));

__device__ __forceinline__ u16 f2bf(float f) {
    unsigned u = __builtin_bit_cast(unsigned, f);
    u += 0x7fffu + ((u >> 16) & 1u);   // RNE
    return (u16)(u >> 16);
}
__device__ __forceinline__ float bf2f(u16 h) {
    unsigned u = ((unsigned)h) << 16;
    return __builtin_bit_cast(float, u);
}

// ---------------- fp32 -> bf16 convert (4 elems/thread, exact grid) ----------------
__global__ __launch_bounds__(256) void f32_to_bf16_k(const float* __restrict__ in,
                                                     u16* __restrict__ out) {
    int i = (blockIdx.x * 256 + threadIdx.x) * 4;
    float4 v = *(const float4*)(in + i);
    uint2 o;
    o.x = (unsigned)f2bf(v.x) | ((unsigned)f2bf(v.y) << 16);
    o.y = (unsigned)f2bf(v.z) | ((unsigned)f2bf(v.w) << 16);
    *(uint2*)(out + i) = o;
}

// ---------------- bf16 GEMM: C[m][n] = sum_k A[m][k]*Bw[n][k] ----------------------
// EPI==0: bf16 out, 3-segment bias (bq|bk|bv), fused RoPE on cols < 2048.
// EPI==1: fp32 out, bias0 only, no RoPE.
template <int EPI>
__global__ __launch_bounds__(256) void gemm_bt(const u16* __restrict__ A,
                                               const u16* __restrict__ Bw,
                                               const float* __restrict__ bias0,
                                               const float* __restrict__ bias1,
                                               const float* __restrict__ bias2,
                                               const int* __restrict__ days,
                                               u16* __restrict__ outB,
                                               float* __restrict__ outF,
                                               int M, int N, int K) {
    __shared__ __align__(16) u16 As[128 * 32];
    __shared__ __align__(16) u16 Bs[128 * 32];
    const int tid = threadIdx.x;
    const int lane = tid & 63;
    const int w = tid >> 6;
    const int wr = w >> 1, wc = w & 1;
    const int lr = lane & 15, lg = lane >> 4;
    const int nbn = N >> 7;
    const int m0 = (blockIdx.x / nbn) << 7;
    const int n0 = (blockIdx.x % nbn) << 7;

    f32x4 acc[4][4] = {};

    const u16* aptr[2];
    const u16* bptr[2];
    int ldsoff[2];
#pragma unroll
    for (int i = 0; i < 2; ++i) {
        int c = (w * 2 + i) * 64 + lane;
        int row = c >> 2, kc = (c & 3) << 3;
        aptr[i] = A + (size_t)(m0 + row) * K + kc;
        bptr[i] = Bw + (size_t)(n0 + row) * K + kc;
        ldsoff[i] = (w * 2 + i) * 512;
    }

    for (int k0 = 0; k0 < K; k0 += 32) {
#pragma unroll
        for (int i = 0; i < 2; ++i) {
            __builtin_amdgcn_global_load_lds(
                (const __attribute__((address_space(1))) void*)(aptr[i] + k0),
                (__attribute__((address_space(3))) void*)(As + ldsoff[i]), 16, 0, 0);
            __builtin_amdgcn_global_load_lds(
                (const __attribute__((address_space(1))) void*)(bptr[i] + k0),
                (__attribute__((address_space(3))) void*)(Bs + ldsoff[i]), 16, 0, 0);
        }
        __syncthreads();
        bf16x8 af[4], bfr[4];
#pragma unroll
        for (int i = 0; i < 4; ++i)
            af[i] = *(const bf16x8*)(As + (wr * 64 + i * 16 + lr) * 32 + lg * 8);
#pragma unroll
        for (int j = 0; j < 4; ++j)
            bfr[j] = *(const bf16x8*)(Bs + (wc * 64 + j * 16 + lr) * 32 + lg * 8);
#pragma unroll
        for (int i = 0; i < 4; ++i)
#pragma unroll
            for (int j = 0; j < 4; ++j)
                acc[i][j] = __builtin_amdgcn_mfma_f32_16x16x32_bf16(af[i], bfr[j],
                                                                    acc[i][j], 0, 0, 0);
        __syncthreads();
    }

    auto bsel = [&](int ng) -> float {
        if (EPI != 0) return bias0[ng];
        return (ng < 1024) ? bias0[ng] : (ng < 2048) ? bias1[ng - 1024] : bias2[ng - 2048];
    };

    if (EPI == 0 && (n0 + wc * 64) < 2048) {
        // q/k region: wave's 64 cols = one full head; pairs (j, j+2) hold (x1, x2).
        const float C1 = -0.41524101186091903f;  // -log2(10000)/32
        const float inv0 = exp2f((float)lr * C1);
        const float inv1 = exp2f((float)(16 + lr) * C1);
#pragma unroll
        for (int i = 0; i < 4; ++i) {
            int mg = m0 + wr * 64 + i * 16 + lg * 4;
#pragma unroll
            for (int r = 0; r < 4; ++r) {
                int m = mg + r;
                int d = days[m];
                int ad = d < 0 ? -d : d;
                ad = ad > 2047 ? 2047 : ad;
                float pos = (float)ad;
#pragma unroll
                for (int j = 0; j < 2; ++j) {
                    int ng1 = n0 + wc * 64 + j * 16 + lr;
                    int ng2 = ng1 + 32;
                    float x1 = acc[i][j][r] + bsel(ng1);
                    float x2 = acc[i][j + 2][r] + bsel(ng2);
                    float ang = pos * (j ? inv1 : inv0);
                    float sn, cs;
                    __sincosf(ang, &sn, &cs);
                    outB[(size_t)m * N + ng1] = f2bf(x1 * cs - x2 * sn);
                    outB[(size_t)m * N + ng2] = f2bf(x2 * cs + x1 * sn);
                }
            }
        }
    } else {
#pragma unroll
        for (int i = 0; i < 4; ++i) {
            int mg = m0 + wr * 64 + i * 16 + lg * 4;
#pragma unroll
            for (int j = 0; j < 4; ++j) {
                int ng = n0 + wc * 64 + j * 16 + lr;
                float bias = bsel(ng);
#pragma unroll
                for (int r = 0; r < 4; ++r) {
                    float v = acc[i][j][r] + bias;
                    if (EPI == 0)
                        outB[(size_t)(mg + r) * N + ng] = f2bf(v);
                    else
                        outF[(size_t)(mg + r) * N + ng] = v;
                }
            }
        }
    }
}

// ---------------- V transpose: qkv v-region -> Vt[b,h,hd,s] ------------------------
__global__ __launch_bounds__(256) void v_transpose_k(const u16* __restrict__ qkv,
                                                     u16* __restrict__ vt) {
    __shared__ u16 tile[64][66];
    int st = blockIdx.x & 31;
    int bh = blockIdx.x >> 5;
    int b = bh >> 4, h = bh & 15;
    int s0 = st * 64;
    int t = threadIdx.x;
#pragma unroll
    for (int it = 0; it < 16; ++it) {
        int idx = it * 256 + t;
        int sr = idx >> 6, c = idx & 63;
        tile[sr][c] = qkv[(size_t)(b * 2048 + s0 + sr) * 3072 + 2048 + h * 64 + c];
    }
    __syncthreads();
#pragma unroll
    for (int it = 0; it < 16; ++it) {
        int idx = it * 256 + t;
        int hd = idx >> 6, sc = idx & 63;
        vt[((size_t)(bh * 64 + hd)) * 2048 + s0 + sc] = tile[sc][hd];
    }
}

// ---------------- flash attention v5 -----------------------------------------------
// Balanced causal pairing + k-split (NS) + FUSED A/B tile processing: each K-frag and
// V-frag is read from LDS once and feeds both q-tiles' MFMAs. Shared per-key decay
// exp (offset by tile-max day, overflow-safe). Fixed-max softmax => k-split partials
// are additive. LDS-staged K/V (both-sides XOR swizzle), double-buffered, counted
// vmcnt.

__device__ __forceinline__ void attn_tile_fused(
    const u16* __restrict__ Ks, const u16* __restrict__ Vs,
    u16* __restrict__ PwB, u16* __restrict__ PwA, const int* __restrict__ dbk,
    float mt_c, float c1,
    bf16x8 bqB0, bf16x8 bqB1, float dq_cB, int qrelB, bool maskB,
    bf16x8 bqA0, bf16x8 bqA1, float dq_cA, int qrelA, bool maskA, bool doA,
    float& lB, f32x4* accB, float& lA, f32x4* accA, int lr, int lg) {
    f32x4 sB[4], sA[4];
    __builtin_amdgcn_s_setprio(1);
#pragma unroll
    for (int st = 0; st < 4; ++st) {
        const int r2 = st * 16 + lr;
        const u16* kr = Ks + r2 * 64;
        bf16x8 ka0 = *(const bf16x8*)(kr + ((lg ^ (r2 & 7)) << 3));
        bf16x8 ka1 = *(const bf16x8*)(kr + (((4 + lg) ^ (r2 & 7)) << 3));
        f32x4 t = {};
        t = __builtin_amdgcn_mfma_f32_16x16x32_bf16(ka0, bqB0, t, 0, 0, 0);
        t = __builtin_amdgcn_mfma_f32_16x16x32_bf16(ka1, bqB1, t, 0, 0, 0);
        sB[st] = t;
        if (doA) {
            f32x4 u = {};
            u = __builtin_amdgcn_mfma_f32_16x16x32_bf16(ka0, bqA0, u, 0, 0, 0);
            u = __builtin_amdgcn_mfma_f32_16x16x32_bf16(ka1, bqA1, u, 0, 0, 0);
            sA[st] = u;
        }
    }
    __builtin_amdgcn_s_setprio(0);
    const float L2E = 1.4426950408889634f;
    const float POFF = 17.312340490667562f;  // 12*log2(e)
    const float eqB = exp2f(mt_c - dq_cB);
    const float eqA = doA ? exp2f(mt_c - dq_cA) : 0.f;
    float ek[4][4];
    float pB[4][4], pA[4][4];
#pragma unroll
    for (int st = 0; st < 4; ++st) {
        int4 dk4 = *(const int4*)(dbk + st * 16 + lg * 4);
#pragma unroll
        for (int r = 0; r < 4; ++r) {
            float dkf = (float)((&dk4.x)[r]);
            ek[st][r] = exp2f(__builtin_fmaf(dkf, c1, -mt_c));  // <= 1
            float vB = sB[st][r] * (ek[st][r] * eqB);
            pB[st][r] = exp2f(__builtin_fmaf(vB, L2E, -POFF));
        }
    }
    if (maskB) {
#pragma unroll
        for (int st = 0; st < 4; ++st)
#pragma unroll
            for (int r = 0; r < 4; ++r)
                pB[st][r] = (st * 16 + lg * 4 + r <= qrelB) ? pB[st][r] : 0.f;
    }
#pragma unroll
    for (int st = 0; st < 4; ++st)
#pragma unroll
        for (int r = 0; r < 4; ++r) lB += pB[st][r];
#pragma unroll
    for (int st = 0; st < 4; ++st) {
        unsigned lo, hi;
        asm("v_cvt_pk_bf16_f32 %0, %1, %2" : "=v"(lo) : "v"(pB[st][0]), "v"(pB[st][1]));
        asm("v_cvt_pk_bf16_f32 %0, %1, %2" : "=v"(hi) : "v"(pB[st][2]), "v"(pB[st][3]));
        uint2 pk;
        pk.x = lo;
        pk.y = hi;
        int chunk = st * 2 + (lg >> 1);
        int idx = lr * 64 + ((chunk ^ (lr & 7)) << 3) + ((lg & 1) << 2);
        *(uint2*)&PwB[idx] = pk;
    }
    if (doA) {
#pragma unroll
        for (int st = 0; st < 4; ++st)
#pragma unroll
            for (int r = 0; r < 4; ++r) {
                float vA = sA[st][r] * (ek[st][r] * eqA);
                pA[st][r] = exp2f(__builtin_fmaf(vA, L2E, -POFF));
            }
        if (maskA) {
#pragma unroll
            for (int st = 0; st < 4; ++st)
#pragma unroll
                for (int r = 0; r < 4; ++r)
                    pA[st][r] = (st * 16 + lg * 4 + r <= qrelA) ? pA[st][r] : 0.f;
        }
#pragma unroll
        for (int st = 0; st < 4; ++st)
#pragma unroll
            for (int r = 0; r < 4; ++r) lA += pA[st][r];
#pragma unroll
        for (int st = 0; st < 4; ++st) {
            unsigned lo, hi;
            asm("v_cvt_pk_bf16_f32 %0, %1, %2"
                : "=v"(lo)
                : "v"(pA[st][0]), "v"(pA[st][1]));
            asm("v_cvt_pk_bf16_f32 %0, %1, %2"
                : "=v"(hi)
                : "v"(pA[st][2]), "v"(pA[st][3]));
            uint2 pk;
            pk.x = lo;
            pk.y = hi;
            int chunk = st * 2 + (lg >> 1);
            int idx = lr * 64 + ((chunk ^ (lr & 7)) << 3) + ((lg & 1) << 2);
            *(uint2*)&PwA[idx] = pk;
        }
    }
    // PV: V-fragments read once, feed both tiles
    __builtin_amdgcn_s_setprio(1);
#pragma unroll
    for (int pv = 0; pv < 2; ++pv) {
        int chunk = pv * 4 + lg;
        bf16x8 paB = *(const bf16x8*)&PwB[lr * 64 + ((chunk ^ (lr & 7)) << 3)];
        bf16x8 paA;
        if (doA) paA = *(const bf16x8*)&PwA[lr * 64 + ((chunk ^ (lr & 7)) << 3)];
#pragma unroll
        for (int c = 0; c < 4; ++c) {
            const int r3 = c * 16 + lr;
            bf16x8 bv = *(const bf16x8*)(Vs + r3 * 64 + ((chunk ^ (r3 & 7)) << 3));
            accB[c] = __builtin_amdgcn_mfma_f32_16x16x32_bf16(paB, bv, accB[c], 0, 0, 0);
            if (doA)
                accA[c] = __builtin_amdgcn_mfma_f32_16x16x32_bf16(paA, bv, accA[c], 0, 0, 0);
        }
    }
    __builtin_amdgcn_s_setprio(0);
}

template <int NS>
__global__ __launch_bounds__(256, NS == 2 ? 3 : 2) void attn_k(
    const u16* __restrict__ qkv, const u16* __restrict__ vt,
    const int* __restrict__ days, const float* __restrict__ decay_p,
    u16* __restrict__ outp, float* __restrict__ l_out) {
    __shared__ __align__(16) u16 Ks[2][4096];
    __shared__ __align__(16) u16 Vs[2][4096];
    __shared__ __align__(16) u16 Plds[4][2048];
    const int tid = threadIdx.x;
    const int lane = tid & 63;
    const int w = tid >> 6;
    const int lr = lane & 15, lg = lane >> 4;
    const int s = (NS == 2) ? (blockIdx.x & 1) : 0;
    const int j = (NS == 2) ? ((blockIdx.x >> 1) & 15) : (blockIdx.x & 15);
    const int bh = (NS == 2) ? (blockIdx.x >> 5) : (blockIdx.x >> 4);
    const int b = bh >> 4, h = bh & 15;
    const int qtB = 31 - j;
    const int qbA = j * 64 + w * 16;
    const int qbB = qtB * 64 + w * 16;
    const float rate = decay_p[0];
    const float c1 = rate * 1.4426950408889634f;

    const u16* qmat = qkv + (size_t)b * 2048 * 3072 + h * 64;
    const u16* kmat = qmat + 1024;
    const u16* vtm = vt + (size_t)bh * 64 * 2048;
    const int* db = days + b * 2048;

    const int cp0 = (w * 2 + 0) * 64 + lane;
    const int cp1 = (w * 2 + 1) * 64 + lane;
    const int r0 = cp0 >> 3, c0 = cp0 & 7;
    const int r1 = cp1 >> 3, c1i = cp1 & 7;
    const u16* ksrc0 = kmat + (size_t)r0 * 3072 + ((c0 ^ (r0 & 7)) << 3);
    const u16* ksrc1 = kmat + (size_t)r1 * 3072 + ((c1i ^ (r1 & 7)) << 3);
    const u16* vsrc0 = vtm + (size_t)r0 * 2048 + ((c0 ^ (r0 & 7)) << 3);
    const u16* vsrc1 = vtm + (size_t)r1 * 2048 + ((c1i ^ (r1 & 7)) << 3);
    const int doff0 = (w * 2 + 0) * 512;
    const int doff1 = (w * 2 + 1) * 512;

#define STAGE(T, BUF)                                                                  \
    do {                                                                               \
        __builtin_amdgcn_global_load_lds(                                              \
            (const __attribute__((address_space(1))) void*)(ksrc0 +                    \
                                                            (size_t)(T) * 64 * 3072), \
            (__attribute__((address_space(3))) void*)(&Ks[BUF][doff0]), 16, 0, 0);     \
        __builtin_amdgcn_global_load_lds(                                              \
            (const __attribute__((address_space(1))) void*)(ksrc1 +                    \
                                                            (size_t)(T) * 64 * 3072), \
            (__attribute__((address_space(3))) void*)(&Ks[BUF][doff1]), 16, 0, 0);     \
        __builtin_amdgcn_global_load_lds(                                              \
            (const __attribute__((address_space(1))) void*)(vsrc0 + (size_t)(T) * 64), \
            (__attribute__((address_space(3))) void*)(&Vs[BUF][doff0]), 16, 0, 0);     \
        __builtin_amdgcn_global_load_lds(                                              \
            (const __attribute__((address_space(1))) void*)(vsrc1 + (size_t)(T) * 64), \
            (__attribute__((address_space(3))) void*)(&Vs[BUF][doff1]), 16, 0, 0);     \
    } while (0)

    bf16x8 bqA0, bqA1, bqB0, bqB1;
    {
        const u16* qpA = qmat + (size_t)(qbA + lr) * 3072 + lg * 8;
        bqA0 = *(const bf16x8*)qpA;
        bqA1 = *(const bf16x8*)(qpA + 32);
        const u16* qpB = qmat + (size_t)(qbB + lr) * 3072 + lg * 8;
        bqB0 = *(const bf16x8*)qpB;
        bqB1 = *(const bf16x8*)(qpB + 32);
    }
    // dq_c = (dq*rate + ln8)*log2e = dq*c1 + 3
    const float dq_cA = (float)db[qbA + lr] * c1 + 3.0f;
    const float dq_cB = (float)db[qbB + lr] * c1 + 3.0f;

    float lA = 0.f, lB = 0.f;
    f32x4 accA[4] = {};
    f32x4 accB[4] = {};

    const int STEP = (NS == 2) ? 2 : 1;
    const int nkt = (NS == 2) ? (((31 - j - s) >> 1) + 1) : (32 - j);
    STAGE(s, 0);
    for (int it = 0; it < nkt; ++it) {
        const int kt = s + it * STEP;
        const int cur = it & 1;
        if (it + 1 < nkt) {
            STAGE(kt + STEP, cur ^ 1);
            asm volatile("s_waitcnt vmcnt(4)" ::: "memory");
        } else {
            asm volatile("s_waitcnt vmcnt(0)" ::: "memory");
        }
        __builtin_amdgcn_s_barrier();
        const int* dbk = db + kt * 64;
        const float mt_c = (float)dbk[63] * c1;  // tile-max day (sorted)
        attn_tile_fused(Ks[cur], Vs[cur], &Plds[w][0], &Plds[w][1024], dbk, mt_c, c1,
                        bqB0, bqB1, dq_cB, w * 16 + lr, kt == qtB,
                        bqA0, bqA1, dq_cA, w * 16 + lr, kt == j, kt <= j,
                        lB, accB, lA, accA, lr, lg);
        __builtin_amdgcn_s_barrier();
    }
#undef STAGE

#pragma unroll
    for (int t = 0; t < 2; ++t) {
        float lp = t ? lA : lB;
        f32x4* acc = t ? accA : accB;
        const int qt = t ? j : qtB;
        float l_full = lp + __shfl_xor(lp, 16);
        l_full += __shfl_xor(l_full, 32);
        if (NS == 1) {
            float inv_[4];
#pragma unroll
            for (int r = 0; r < 4; ++r) inv_[r] = 1.0f / __shfl(l_full, lg * 4 + r);
#pragma unroll
            for (int c = 0; c < 4; ++c)
#pragma unroll
                for (int r = 0; r < 4; ++r) {
                    const int qg = qt * 64 + w * 16 + lg * 4 + r;
                    outp[(size_t)(b * 2048 + qg) * 1024 + h * 64 + c * 16 + lr] =
                        f2bf(acc[c][r] * inv_[r]);
                }
        } else {
            u16* nbase = outp + (((size_t)s * 32 + bh) * 32 + qt) * 4096;
#pragma unroll
            for (int c = 0; c < 4; ++c)
#pragma unroll
                for (int r = 0; r < 4; ++r)
                    nbase[(w * 16 + lg * 4 + r) * 64 + c * 16 + lr] = f2bf(acc[c][r]);
            if (lg == 0)
                l_out[((size_t)s * 32 + bh) * 32 * 64 + qt * 64 + w * 16 + lr] = l_full;
        }
    }
}

// ---------------- combine: attb = (num0+num1)/(l0+l1) ------------------------------
__global__ __launch_bounds__(256) void attn_combine_k(const u16* __restrict__ num,
                                                      const float* __restrict__ lbuf,
                                                      u16* __restrict__ attb) {
    int idx = blockIdx.x * 256 + threadIdx.x;  // 1,048,576 total
    int hd4 = idx & 15;
    int row = (idx >> 4) & 63;
    int qtbh = idx >> 10;  // bh*32 + qt
    int qt = qtbh & 31, bh = qtbh >> 5;
    const size_t SPL = (size_t)32 * 32 * 64 * 64;
    size_t nidx = ((size_t)qtbh * 64 + row) * 64 + hd4 * 4;
    uint2 a = *(const uint2*)(num + nidx);
    uint2 bb = *(const uint2*)(num + SPL + nidx);
    float l = lbuf[qtbh * 64 + row] + lbuf[32 * 32 * 64 + qtbh * 64 + row];
    float invl = 1.0f / l;
    float s0 = (bf2f((u16)a.x) + bf2f((u16)bb.x)) * invl;
    float s1 = (bf2f((u16)(a.x >> 16)) + bf2f((u16)(bb.x >> 16))) * invl;
    float s2 = (bf2f((u16)a.y) + bf2f((u16)bb.y)) * invl;
    float s3 = (bf2f((u16)(a.y >> 16)) + bf2f((u16)(bb.y >> 16))) * invl;
    int b = bh >> 4, h = bh & 15;
    int m = b * 2048 + qt * 64 + row;
    int col = h * 64 + hd4 * 4;
    uint2 o;
    o.x = (unsigned)f2bf(s0) | ((unsigned)f2bf(s1) << 16);
    o.y = (unsigned)f2bf(s2) | ((unsigned)f2bf(s3) << 16);
    *(uint2*)(attb + (size_t)m * 1024 + col) = o;
}

// ---------------- launch -----------------------------------------------------------
extern "C" void kernel_launch(void* const* d_in, const int* in_sizes, int n_in,
                              void* d_out, int out_size, void* d_ws, size_t ws_size,
                              hipStream_t stream) {
    const float* x = (const float*)d_in[0];
    const float* Wq = (const float*)d_in[1];
    const float* bq = (const float*)d_in[2];
    const float* Wk = (const float*)d_in[3];
    const float* bk = (const float*)d_in[4];
    const float* Wv = (const float*)d_in[5];
    const float* bv = (const float*)d_in[6];
    const float* Wo = (const float*)d_in[7];
    const float* bo = (const float*)d_in[8];
    const float* decay = (const float*)d_in[9];
    const int* days = (const int*)d_in[11];
    float* out = (float*)d_out;

    char* ws = (char*)d_ws;
    u16* xb = (u16*)(ws);                   //  8 MB: x bf16 [4096][1024]
    u16* wqkv = (u16*)(ws + 8388608);       //  6 MB: [Wq;Wk;Wv] bf16 [3072][1024]
    u16* wo = (u16*)(ws + 14680064);        //  2 MB: Wo bf16 [1024][1024]
    u16* qkvb = (u16*)(ws + 16777216);      // 24 MB: qkv bf16 [4096][3072]
    u16* vtb = (u16*)(ws + 41943040);       //  8 MB: Vt bf16 [32][64][2048]
    u16* attb = (u16*)(ws + 50331648);      //  8 MB: attn out bf16 [4096][1024]
    u16* numb = (u16*)(ws + 58720256);      // 16 MB: partial numerators bf16 [2][...]
    float* lbuf = (float*)(ws + 75497472);  // 0.5 MB: partial l fp32 [2][32][32][64]
    const size_t WS_NEED = 76021760;

    f32_to_bf16_k<<<4096, 256, 0, stream>>>(x, xb);
    f32_to_bf16_k<<<1024, 256, 0, stream>>>(Wq, wqkv);
    f32_to_bf16_k<<<1024, 256, 0, stream>>>(Wk, wqkv + 1048576);
    f32_to_bf16_k<<<1024, 256, 0, stream>>>(Wv, wqkv + 2097152);
    f32_to_bf16_k<<<1024, 256, 0, stream>>>(Wo, wo);

    gemm_bt<0><<<768, 256, 0, stream>>>(xb, wqkv, bq, bk, bv, days, qkvb, nullptr,
                                        4096, 3072, 1024);
    v_transpose_k<<<1024, 256, 0, stream>>>(qkvb, vtb);
    if (ws_size >= WS_NEED) {
        attn_k<2><<<1024, 256, 0, stream>>>(qkvb, vtb, days, decay, numb, lbuf);
        attn_combine_k<<<4096, 256, 0, stream>>>(numb, lbuf, attb);
    } else {
        attn_k<1><<<512, 256, 0, stream>>>(qkvb, vtb, days, decay, attb, nullptr);
    }
    gemm_bt<1><<<256, 256, 0, stream>>>(attb, wo, bo, nullptr, nullptr, days, nullptr,
                                        out, 4096, 1024, 1024);
}

// Round 7
// 155.652 us; speedup vs baseline: 1.1035x; 1.1035x over previous
//
#include <hip/hip_runtime.h>
#include <hip/hip_bf16.h>

// B=2, S=2048, D=1024, H=16, HD=64. fp32 in, fp32 out, bf16-tolerance threshold.
// Pipeline: convert->bf16 | QKV GEMM (mfma, fused bias+RoPE) | V-transpose |
//           flash attn (8-wave block, wave-group k-parity split, fixed-max softmax) |
//           out GEMM.

typedef unsigned short u16;
typedef short bf16x8 __attribute__((ext_vector_type(8)));
typedef float f32x4 __attribute__((ext_vector_type(4)));

__device__ __forceinline__ u16 f2bf(float f) {
    unsigned u = __builtin_bit_cast(unsigned, f);
    u += 0x7fffu + ((u >> 16) & 1u);   // RNE
    return (u16)(u >> 16);
}
__device__ __forceinline__ float bf2f(u16 h) {
    unsigned u = ((unsigned)h) << 16;
    return __builtin_bit_cast(float, u);
}

// ---------------- fp32 -> bf16 convert (4 elems/thread, exact grid) ----------------
__global__ __launch_bounds__(256) void f32_to_bf16_k(const float* __restrict__ in,
                                                     u16* __restrict__ out) {
    int i = (blockIdx.x * 256 + threadIdx.x) * 4;
    float4 v = *(const float4*)(in + i);
    uint2 o;
    o.x = (unsigned)f2bf(v.x) | ((unsigned)f2bf(v.y) << 16);
    o.y = (unsigned)f2bf(v.z) | ((unsigned)f2bf(v.w) << 16);
    *(uint2*)(out + i) = o;
}

// ---------------- bf16 GEMM: C[m][n] = sum_k A[m][k]*Bw[n][k] ----------------------
// EPI==0: bf16 out, 3-segment bias (bq|bk|bv), fused RoPE on cols < 2048.
// EPI==1: fp32 out, bias0 only, no RoPE.
template <int EPI>
__global__ __launch_bounds__(256) void gemm_bt(const u16* __restrict__ A,
                                               const u16* __restrict__ Bw,
                                               const float* __restrict__ bias0,
                                               const float* __restrict__ bias1,
                                               const float* __restrict__ bias2,
                                               const int* __restrict__ days,
                                               u16* __restrict__ outB,
                                               float* __restrict__ outF,
                                               int M, int N, int K) {
    __shared__ __align__(16) u16 As[128 * 32];
    __shared__ __align__(16) u16 Bs[128 * 32];
    const int tid = threadIdx.x;
    const int lane = tid & 63;
    const int w = tid >> 6;
    const int wr = w >> 1, wc = w & 1;
    const int lr = lane & 15, lg = lane >> 4;
    const int nbn = N >> 7;
    const int m0 = (blockIdx.x / nbn) << 7;
    const int n0 = (blockIdx.x % nbn) << 7;

    f32x4 acc[4][4] = {};

    const u16* aptr[2];
    const u16* bptr[2];
    int ldsoff[2];
#pragma unroll
    for (int i = 0; i < 2; ++i) {
        int c = (w * 2 + i) * 64 + lane;
        int row = c >> 2, kc = (c & 3) << 3;
        aptr[i] = A + (size_t)(m0 + row) * K + kc;
        bptr[i] = Bw + (size_t)(n0 + row) * K + kc;
        ldsoff[i] = (w * 2 + i) * 512;
    }

    for (int k0 = 0; k0 < K; k0 += 32) {
#pragma unroll
        for (int i = 0; i < 2; ++i) {
            __builtin_amdgcn_global_load_lds(
                (const __attribute__((address_space(1))) void*)(aptr[i] + k0),
                (__attribute__((address_space(3))) void*)(As + ldsoff[i]), 16, 0, 0);
            __builtin_amdgcn_global_load_lds(
                (const __attribute__((address_space(1))) void*)(bptr[i] + k0),
                (__attribute__((address_space(3))) void*)(Bs + ldsoff[i]), 16, 0, 0);
        }
        __syncthreads();
        bf16x8 af[4], bfr[4];
#pragma unroll
        for (int i = 0; i < 4; ++i)
            af[i] = *(const bf16x8*)(As + (wr * 64 + i * 16 + lr) * 32 + lg * 8);
#pragma unroll
        for (int j = 0; j < 4; ++j)
            bfr[j] = *(const bf16x8*)(Bs + (wc * 64 + j * 16 + lr) * 32 + lg * 8);
#pragma unroll
        for (int i = 0; i < 4; ++i)
#pragma unroll
            for (int j = 0; j < 4; ++j)
                acc[i][j] = __builtin_amdgcn_mfma_f32_16x16x32_bf16(af[i], bfr[j],
                                                                    acc[i][j], 0, 0, 0);
        __syncthreads();
    }

    auto bsel = [&](int ng) -> float {
        if (EPI != 0) return bias0[ng];
        return (ng < 1024) ? bias0[ng] : (ng < 2048) ? bias1[ng - 1024] : bias2[ng - 2048];
    };

    if (EPI == 0 && (n0 + wc * 64) < 2048) {
        // q/k region: wave's 64 cols = one full head; pairs (j, j+2) hold (x1, x2).
        const float C1 = -0.41524101186091903f;  // -log2(10000)/32
        const float inv0 = exp2f((float)lr * C1);
        const float inv1 = exp2f((float)(16 + lr) * C1);
#pragma unroll
        for (int i = 0; i < 4; ++i) {
            int mg = m0 + wr * 64 + i * 16 + lg * 4;
#pragma unroll
            for (int r = 0; r < 4; ++r) {
                int m = mg + r;
                int d = days[m];
                int ad = d < 0 ? -d : d;
                ad = ad > 2047 ? 2047 : ad;
                float pos = (float)ad;
#pragma unroll
                for (int j = 0; j < 2; ++j) {
                    int ng1 = n0 + wc * 64 + j * 16 + lr;
                    int ng2 = ng1 + 32;
                    float x1 = acc[i][j][r] + bsel(ng1);
                    float x2 = acc[i][j + 2][r] + bsel(ng2);
                    float ang = pos * (j ? inv1 : inv0);
                    float sn, cs;
                    __sincosf(ang, &sn, &cs);
                    outB[(size_t)m * N + ng1] = f2bf(x1 * cs - x2 * sn);
                    outB[(size_t)m * N + ng2] = f2bf(x2 * cs + x1 * sn);
                }
            }
        }
    } else {
#pragma unroll
        for (int i = 0; i < 4; ++i) {
            int mg = m0 + wr * 64 + i * 16 + lg * 4;
#pragma unroll
            for (int j = 0; j < 4; ++j) {
                int ng = n0 + wc * 64 + j * 16 + lr;
                float bias = bsel(ng);
#pragma unroll
                for (int r = 0; r < 4; ++r) {
                    float v = acc[i][j][r] + bias;
                    if (EPI == 0)
                        outB[(size_t)(mg + r) * N + ng] = f2bf(v);
                    else
                        outF[(size_t)(mg + r) * N + ng] = v;
                }
            }
        }
    }
}

// ---------------- V transpose: qkv v-region -> Vt[b,h,hd,s] ------------------------
__global__ __launch_bounds__(256) void v_transpose_k(const u16* __restrict__ qkv,
                                                     u16* __restrict__ vt) {
    __shared__ u16 tile[64][66];
    int st = blockIdx.x & 31;
    int bh = blockIdx.x >> 5;
    int b = bh >> 4, h = bh & 15;
    int s0 = st * 64;
    int t = threadIdx.x;
#pragma unroll
    for (int it = 0; it < 16; ++it) {
        int idx = it * 256 + t;
        int sr = idx >> 6, c = idx & 63;
        tile[sr][c] = qkv[(size_t)(b * 2048 + s0 + sr) * 3072 + 2048 + h * 64 + c];
    }
    __syncthreads();
#pragma unroll
    for (int it = 0; it < 16; ++it) {
        int idx = it * 256 + t;
        int hd = idx >> 6, sc = idx & 63;
        vt[((size_t)(bh * 64 + hd)) * 2048 + s0 + sc] = tile[sc][hd];
    }
}

// ---------------- flash attention v6 -----------------------------------------------
// 512-thread block (8 waves), balanced causal pairing: block j owns q-tiles {j,31-j}.
// Wave-group k-parity split: waves 0-3 (group 0) process even k-tiles, waves 4-7
// (group 1) odd k-tiles; fixed-max softmax => group partials (numerator, l) are
// additive, merged through LDS at the end (no global combine). Per-wave code is the
// proven v3 tile: swapped QK^T, lane-local softmax, exp2-folded decay, cvt_pk pack,
// LDS-staged K/V (both-sides XOR swizzle), per-group double-buffer, counted vmcnt.
// LDS 80KB -> exactly 2 blocks/CU = 16 waves/CU (2x the v3 occupancy).

__device__ __forceinline__ void attn_tile(const u16* __restrict__ Ks,
                                          const u16* __restrict__ Vs,
                                          u16* __restrict__ Pw,
                                          const int* __restrict__ dbk,
                                          bf16x8 bq0, bf16x8 bq1, float dq_c, float c1,
                                          int qrel, bool domask,
                                          float& l_part, f32x4* acc, int lr, int lg) {
    f32x4 st_acc[4];
    __builtin_amdgcn_s_setprio(1);
#pragma unroll
    for (int st = 0; st < 4; ++st) {
        const int r2 = st * 16 + lr;
        const u16* kr = Ks + r2 * 64;
        bf16x8 ka0 = *(const bf16x8*)(kr + ((lg ^ (r2 & 7)) << 3));
        bf16x8 ka1 = *(const bf16x8*)(kr + (((4 + lg) ^ (r2 & 7)) << 3));
        f32x4 t = {};
        t = __builtin_amdgcn_mfma_f32_16x16x32_bf16(ka0, bq0, t, 0, 0, 0);
        t = __builtin_amdgcn_mfma_f32_16x16x32_bf16(ka1, bq1, t, 0, 0, 0);
        st_acc[st] = t;
    }
    __builtin_amdgcn_s_setprio(0);
    const float L2E = 1.4426950408889634f;
    const float POFF = 17.312340490667562f;  // 12*log2(e)
    float p[4][4];
#pragma unroll
    for (int st = 0; st < 4; ++st) {
        int4 dk4 = *(const int4*)(dbk + st * 16 + lg * 4);
#pragma unroll
        for (int r = 0; r < 4; ++r) {
            float dkf = (float)((&dk4.x)[r]);
            float dec = exp2f(__builtin_fmaf(dkf, c1, -dq_c));  // decay/8
            float v = st_acc[st][r] * dec;
            p[st][r] = exp2f(__builtin_fmaf(v, L2E, -POFF));
        }
    }
    if (domask) {
#pragma unroll
        for (int st = 0; st < 4; ++st)
#pragma unroll
            for (int r = 0; r < 4; ++r)
                p[st][r] = (st * 16 + lg * 4 + r <= qrel) ? p[st][r] : 0.f;
    }
#pragma unroll
    for (int st = 0; st < 4; ++st)
#pragma unroll
        for (int r = 0; r < 4; ++r) l_part += p[st][r];
#pragma unroll
    for (int st = 0; st < 4; ++st) {
        unsigned lo, hi;
        asm("v_cvt_pk_bf16_f32 %0, %1, %2" : "=v"(lo) : "v"(p[st][0]), "v"(p[st][1]));
        asm("v_cvt_pk_bf16_f32 %0, %1, %2" : "=v"(hi) : "v"(p[st][2]), "v"(p[st][3]));
        uint2 pk;
        pk.x = lo;
        pk.y = hi;
        int chunk = st * 2 + (lg >> 1);
        int idx = lr * 64 + ((chunk ^ (lr & 7)) << 3) + ((lg & 1) << 2);
        *(uint2*)&Pw[idx] = pk;
    }
    __builtin_amdgcn_s_setprio(1);
#pragma unroll
    for (int pv = 0; pv < 2; ++pv) {
        int chunk = pv * 4 + lg;
        bf16x8 pa = *(const bf16x8*)&Pw[lr * 64 + ((chunk ^ (lr & 7)) << 3)];
#pragma unroll
        for (int c = 0; c < 4; ++c) {
            const int r3 = c * 16 + lr;
            bf16x8 bv = *(const bf16x8*)(Vs + r3 * 64 + ((chunk ^ (r3 & 7)) << 3));
            acc[c] = __builtin_amdgcn_mfma_f32_16x16x32_bf16(pa, bv, acc[c], 0, 0, 0);
        }
    }
    __builtin_amdgcn_s_setprio(0);
}

__global__ __launch_bounds__(512, 4) void attn_k(const u16* __restrict__ qkv,
                                                 const u16* __restrict__ vt,
                                                 const int* __restrict__ days,
                                                 const float* __restrict__ decay_p,
                                                 u16* __restrict__ attn_out) {
    __shared__ __align__(16) u16 Ks[4][4096];   // 4 tile-slots: (pair-parity)*2 + group
    __shared__ __align__(16) u16 Vs[4][4096];
    __shared__ __align__(16) u16 Plds[8][1024];
    const int tid = threadIdx.x;
    const int lane = tid & 63;
    const int w = tid >> 6;      // 0..7
    const int qw = w & 3;        // q-row subtile within the 64-row q-tiles
    const int g = w >> 2;        // k-parity group
    const int lr = lane & 15, lg = lane >> 4;
    // bijective XCD swizzle (512 = 8 XCDs x 64): consecutive bh share an XCD's L2
    const int wg = (blockIdx.x & 7) * 64 + (blockIdx.x >> 3);
    const int j = wg & 15;
    const int bh = wg >> 4;
    const int b = bh >> 4, h = bh & 15;
    const int qtB = 31 - j;
    const int qbA = j * 64 + qw * 16;
    const int qbB = qtB * 64 + qw * 16;
    const float rate = decay_p[0];
    const float c1 = rate * 1.4426950408889634f;

    const u16* qmat = qkv + (size_t)b * 2048 * 3072 + h * 64;
    const u16* kmat = qmat + 1024;
    const u16* vtm = vt + (size_t)bh * 64 * 2048;
    const int* db = days + b * 2048;

    // staging: group's 4 waves (qw=0..3) cover the 512 16B-chunks of one tile.
    // LDS dest linear; global source pre-applies the read-side XOR swizzle.
    const int cp0 = (qw * 2 + 0) * 64 + lane;
    const int cp1 = (qw * 2 + 1) * 64 + lane;
    const int r0 = cp0 >> 3, c0 = cp0 & 7;
    const int r1 = cp1 >> 3, c1i = cp1 & 7;
    const u16* ksrc0 = kmat + (size_t)r0 * 3072 + ((c0 ^ (r0 & 7)) << 3);
    const u16* ksrc1 = kmat + (size_t)r1 * 3072 + ((c1i ^ (r1 & 7)) << 3);
    const u16* vsrc0 = vtm + (size_t)r0 * 2048 + ((c0 ^ (r0 & 7)) << 3);
    const u16* vsrc1 = vtm + (size_t)r1 * 2048 + ((c1i ^ (r1 & 7)) << 3);
    const int doff0 = (qw * 2 + 0) * 512;
    const int doff1 = (qw * 2 + 1) * 512;

#define STAGE(T, SLOT)                                                                 \
    do {                                                                               \
        __builtin_amdgcn_global_load_lds(                                              \
            (const __attribute__((address_space(1))) void*)(ksrc0 +                    \
                                                            (size_t)(T) * 64 * 3072), \
            (__attribute__((address_space(3))) void*)(&Ks[SLOT][doff0]), 16, 0, 0);    \
        __builtin_amdgcn_global_load_lds(                                              \
            (const __attribute__((address_space(1))) void*)(ksrc1 +                    \
                                                            (size_t)(T) * 64 * 3072), \
            (__attribute__((address_space(3))) void*)(&Ks[SLOT][doff1]), 16, 0, 0);    \
        __builtin_amdgcn_global_load_lds(                                              \
            (const __attribute__((address_space(1))) void*)(vsrc0 + (size_t)(T) * 64), \
            (__attribute__((address_space(3))) void*)(&Vs[SLOT][doff0]), 16, 0, 0);    \
        __builtin_amdgcn_global_load_lds(                                              \
            (const __attribute__((address_space(1))) void*)(vsrc1 + (size_t)(T) * 64), \
            (__attribute__((address_space(3))) void*)(&Vs[SLOT][doff1]), 16, 0, 0);    \
    } while (0)

    STAGE(g, g);  // pair 0: group g stages tile g into slot g

    bf16x8 bqA0, bqA1, bqB0, bqB1;
    {
        const u16* qpA = qmat + (size_t)(qbA + lr) * 3072 + lg * 8;
        bqA0 = *(const bf16x8*)qpA;
        bqA1 = *(const bf16x8*)(qpA + 32);
        const u16* qpB = qmat + (size_t)(qbB + lr) * 3072 + lg * 8;
        bqB0 = *(const bf16x8*)qpB;
        bqB1 = *(const bf16x8*)(qpB + 32);
    }
    // dq_c = (dq*rate + ln8)*log2e = dq*c1 + 3
    const float dq_cA = (float)db[qbA + lr] * c1 + 3.0f;
    const float dq_cB = (float)db[qbB + lr] * c1 + 3.0f;

    float lA = 0.f, lB = 0.f;
    f32x4 accA[4] = {};
    f32x4 accB[4] = {};

    const int nkt = (33 - j) >> 1;  // ceil((32-j)/2) tile-pairs
    for (int it = 0; it < nkt; ++it) {
        const int kt = 2 * it + g;
        const int cur = ((it & 1) << 1) + g;
        if (it + 1 < nkt) {
            STAGE(2 * (it + 1) + g, (((it + 1) & 1) << 1) + g);
            asm volatile("s_waitcnt vmcnt(4)" ::: "memory");
        } else {
            asm volatile("s_waitcnt vmcnt(0)" ::: "memory");
        }
        __builtin_amdgcn_s_barrier();
        const int* dbk = db + kt * 64;
        if (kt <= qtB)
            attn_tile(Ks[cur], Vs[cur], Plds[w], dbk, bqB0, bqB1, dq_cB, c1,
                      qw * 16 + lr, kt == qtB, lB, accB, lr, lg);
        if (kt <= j)
            attn_tile(Ks[cur], Vs[cur], Plds[w], dbk, bqA0, bqA1, dq_cA, c1,
                      qw * 16 + lr, kt == j, lA, accA, lr, lg);
        __builtin_amdgcn_s_barrier();
    }
#undef STAGE

    // merge group partials through LDS, then group 0 writes output
    float* xch = (float*)&Plds[0][0];  // 4096 floats = 4 qw-regions x 64 lanes x 16
    float* lx = (float*)&Ks[0][0];     // l exchange
#pragma unroll
    for (int t = 0; t < 2; ++t) {
        float lp = t ? lA : lB;
        f32x4* acc = t ? accA : accB;
        const int qt = t ? j : qtB;
        __syncthreads();
        if (g == 1) {
            float* dst = xch + qw * 1024 + lane * 16;
#pragma unroll
            for (int c = 0; c < 4; ++c) *(f32x4*)(dst + c * 4) = acc[c];
            lx[qw * 64 + lane] = lp;
        }
        __syncthreads();
        if (g == 0) {
            const float* src = xch + qw * 1024 + lane * 16;
#pragma unroll
            for (int c = 0; c < 4; ++c) acc[c] += *(const f32x4*)(src + c * 4);
            lp += lx[qw * 64 + lane];
            float l_full = lp + __shfl_xor(lp, 16);
            l_full += __shfl_xor(l_full, 32);
            float inv_[4];
#pragma unroll
            for (int r = 0; r < 4; ++r) inv_[r] = 1.0f / __shfl(l_full, lg * 4 + r);
#pragma unroll
            for (int c = 0; c < 4; ++c)
#pragma unroll
                for (int r = 0; r < 4; ++r) {
                    const int qg = qt * 64 + qw * 16 + lg * 4 + r;
                    attn_out[(size_t)(b * 2048 + qg) * 1024 + h * 64 + c * 16 + lr] =
                        f2bf(acc[c][r] * inv_[r]);
                }
        }
    }
}

// ---------------- launch -----------------------------------------------------------
extern "C" void kernel_launch(void* const* d_in, const int* in_sizes, int n_in,
                              void* d_out, int out_size, void* d_ws, size_t ws_size,
                              hipStream_t stream) {
    const float* x = (const float*)d_in[0];
    const float* Wq = (const float*)d_in[1];
    const float* bq = (const float*)d_in[2];
    const float* Wk = (const float*)d_in[3];
    const float* bk = (const float*)d_in[4];
    const float* Wv = (const float*)d_in[5];
    const float* bv = (const float*)d_in[6];
    const float* Wo = (const float*)d_in[7];
    const float* bo = (const float*)d_in[8];
    const float* decay = (const float*)d_in[9];
    const int* days = (const int*)d_in[11];
    float* out = (float*)d_out;

    char* ws = (char*)d_ws;
    u16* xb = (u16*)(ws);                   //  8 MB: x bf16 [4096][1024]
    u16* wqkv = (u16*)(ws + 8388608);       //  6 MB: [Wq;Wk;Wv] bf16 [3072][1024]
    u16* wo = (u16*)(ws + 14680064);        //  2 MB: Wo bf16 [1024][1024]
    u16* qkvb = (u16*)(ws + 16777216);      // 24 MB: qkv bf16 [4096][3072]
    u16* vtb = (u16*)(ws + 41943040);       //  8 MB: Vt bf16 [32][64][2048]
    u16* attb = (u16*)(ws + 50331648);      //  8 MB: attn out bf16 [4096][1024]

    f32_to_bf16_k<<<4096, 256, 0, stream>>>(x, xb);
    f32_to_bf16_k<<<1024, 256, 0, stream>>>(Wq, wqkv);
    f32_to_bf16_k<<<1024, 256, 0, stream>>>(Wk, wqkv + 1048576);
    f32_to_bf16_k<<<1024, 256, 0, stream>>>(Wv, wqkv + 2097152);
    f32_to_bf16_k<<<1024, 256, 0, stream>>>(Wo, wo);

    gemm_bt<0><<<768, 256, 0, stream>>>(xb, wqkv, bq, bk, bv, days, qkvb, nullptr,
                                        4096, 3072, 1024);
    v_transpose_k<<<1024, 256, 0, stream>>>(qkvb, vtb);
    attn_k<<<512, 512, 0, stream>>>(qkvb, vtb, days, decay, attb);
    gemm_bt<1><<<256, 256, 0, stream>>>(attb, wo, bo, nullptr, nullptr, days, nullptr,
                                        out, 4096, 1024, 1024);
}

// Round 10
// 148.876 us; speedup vs baseline: 1.1537x; 1.0455x over previous
//
#include <hip/hip_runtime.h>
#include <hip/hip_bf16.h>

// B=2, S=2048, D=1024, H=16, HD=64. fp32 in, fp32 out, bf16-tolerance threshold.
// Pipeline: convert->bf16 (merged kernel, under test) | QKV GEMM (fused bias+RoPE) |
//           V-transpose | flash attn (round-7 proven v6: 8-wave, k-parity groups) |
//           out GEMM.

typedef unsigned short u16;
typedef short bf16x8 __attribute__((ext_vector_type(8)));
typedef float f32x4 __attribute__((ext_vector_type(4)));

__device__ __forceinline__ u16 f2bf(float f) {
    unsigned u = __builtin_bit_cast(unsigned, f);
    u += 0x7fffu + ((u >> 16) & 1u);   // RNE
    return (u16)(u >> 16);
}
__device__ __forceinline__ float bf2f(u16 h) {
    unsigned u = ((unsigned)h) << 16;
    return __builtin_bit_cast(float, u);
}

// ---------------- fused fp32 -> bf16 convert for all 5 tensors ---------------------
__global__ __launch_bounds__(256) void convert_all_k(const float* __restrict__ x,
                                                     const float* __restrict__ wq,
                                                     const float* __restrict__ wk,
                                                     const float* __restrict__ wv,
                                                     const float* __restrict__ wo_,
                                                     u16* __restrict__ xb,
                                                     u16* __restrict__ wqkv,
                                                     u16* __restrict__ wob) {
    int i = (blockIdx.x * 256 + threadIdx.x) * 4;
    const float* src;
    u16* dst;
    int off;
    if (i < 4194304) {
        src = x; dst = xb; off = i;
    } else if (i < 5242880) {
        src = wq; dst = wqkv; off = i - 4194304;
    } else if (i < 6291456) {
        src = wk; dst = wqkv + 1048576; off = i - 5242880;
    } else if (i < 7340032) {
        src = wv; dst = wqkv + 2097152; off = i - 6291456;
    } else {
        src = wo_; dst = wob; off = i - 7340032;
    }
    float4 v = *(const float4*)(src + off);
    uint2 o;
    o.x = (unsigned)f2bf(v.x) | ((unsigned)f2bf(v.y) << 16);
    o.y = (unsigned)f2bf(v.z) | ((unsigned)f2bf(v.w) << 16);
    *(uint2*)(dst + off) = o;
}

// ---------------- bf16 GEMM: C[m][n] = sum_k A[m][k]*Bw[n][k] ----------------------
// EPI==0: bf16 out, 3-segment bias (bq|bk|bv), fused RoPE on cols < 2048.
// EPI==1: fp32 out, bias0 only, no RoPE.
template <int EPI>
__global__ __launch_bounds__(256) void gemm_bt(const u16* __restrict__ A,
                                               const u16* __restrict__ Bw,
                                               const float* __restrict__ bias0,
                                               const float* __restrict__ bias1,
                                               const float* __restrict__ bias2,
                                               const int* __restrict__ days,
                                               u16* __restrict__ outB,
                                               float* __restrict__ outF,
                                               int M, int N, int K) {
    __shared__ __align__(16) u16 As[128 * 32];
    __shared__ __align__(16) u16 Bs[128 * 32];
    const int tid = threadIdx.x;
    const int lane = tid & 63;
    const int w = tid >> 6;
    const int wr = w >> 1, wc = w & 1;
    const int lr = lane & 15, lg = lane >> 4;
    const int nbn = N >> 7;
    const int m0 = (blockIdx.x / nbn) << 7;
    const int n0 = (blockIdx.x % nbn) << 7;

    f32x4 acc[4][4] = {};

    const u16* aptr[2];
    const u16* bptr[2];
    int ldsoff[2];
#pragma unroll
    for (int i = 0; i < 2; ++i) {
        int c = (w * 2 + i) * 64 + lane;
        int row = c >> 2, kc = (c & 3) << 3;
        aptr[i] = A + (size_t)(m0 + row) * K + kc;
        bptr[i] = Bw + (size_t)(n0 + row) * K + kc;
        ldsoff[i] = (w * 2 + i) * 512;
    }

    for (int k0 = 0; k0 < K; k0 += 32) {
#pragma unroll
        for (int i = 0; i < 2; ++i) {
            __builtin_amdgcn_global_load_lds(
                (const __attribute__((address_space(1))) void*)(aptr[i] + k0),
                (__attribute__((address_space(3))) void*)(As + ldsoff[i]), 16, 0, 0);
            __builtin_amdgcn_global_load_lds(
                (const __attribute__((address_space(1))) void*)(bptr[i] + k0),
                (__attribute__((address_space(3))) void*)(Bs + ldsoff[i]), 16, 0, 0);
        }
        __syncthreads();
        bf16x8 af[4], bfr[4];
#pragma unroll
        for (int i = 0; i < 4; ++i)
            af[i] = *(const bf16x8*)(As + (wr * 64 + i * 16 + lr) * 32 + lg * 8);
#pragma unroll
        for (int j = 0; j < 4; ++j)
            bfr[j] = *(const bf16x8*)(Bs + (wc * 64 + j * 16 + lr) * 32 + lg * 8);
#pragma unroll
        for (int i = 0; i < 4; ++i)
#pragma unroll
            for (int j = 0; j < 4; ++j)
                acc[i][j] = __builtin_amdgcn_mfma_f32_16x16x32_bf16(af[i], bfr[j],
                                                                    acc[i][j], 0, 0, 0);
        __syncthreads();
    }

    auto bsel = [&](int ng) -> float {
        if (EPI != 0) return bias0[ng];
        return (ng < 1024) ? bias0[ng] : (ng < 2048) ? bias1[ng - 1024] : bias2[ng - 2048];
    };

    if (EPI == 0 && (n0 + wc * 64) < 2048) {
        // q/k region: wave's 64 cols = one full head; pairs (j, j+2) hold (x1, x2).
        const float C1 = -0.41524101186091903f;  // -log2(10000)/32
        const float inv0 = exp2f((float)lr * C1);
        const float inv1 = exp2f((float)(16 + lr) * C1);
#pragma unroll
        for (int i = 0; i < 4; ++i) {
            int mg = m0 + wr * 64 + i * 16 + lg * 4;
#pragma unroll
            for (int r = 0; r < 4; ++r) {
                int m = mg + r;
                int d = days[m];
                int ad = d < 0 ? -d : d;
                ad = ad > 2047 ? 2047 : ad;
                float pos = (float)ad;
#pragma unroll
                for (int j = 0; j < 2; ++j) {
                    int ng1 = n0 + wc * 64 + j * 16 + lr;
                    int ng2 = ng1 + 32;
                    float x1 = acc[i][j][r] + bsel(ng1);
                    float x2 = acc[i][j + 2][r] + bsel(ng2);
                    float ang = pos * (j ? inv1 : inv0);
                    float sn, cs;
                    __sincosf(ang, &sn, &cs);
                    outB[(size_t)m * N + ng1] = f2bf(x1 * cs - x2 * sn);
                    outB[(size_t)m * N + ng2] = f2bf(x2 * cs + x1 * sn);
                }
            }
        }
    } else {
#pragma unroll
        for (int i = 0; i < 4; ++i) {
            int mg = m0 + wr * 64 + i * 16 + lg * 4;
#pragma unroll
            for (int j = 0; j < 4; ++j) {
                int ng = n0 + wc * 64 + j * 16 + lr;
                float bias = bsel(ng);
#pragma unroll
                for (int r = 0; r < 4; ++r) {
                    float v = acc[i][j][r] + bias;
                    if (EPI == 0)
                        outB[(size_t)(mg + r) * N + ng] = f2bf(v);
                    else
                        outF[(size_t)(mg + r) * N + ng] = v;
                }
            }
        }
    }
}

// ---------------- V transpose: qkv v-region -> Vt[b,h,hd,s] ------------------------
__global__ __launch_bounds__(256) void v_transpose_k(const u16* __restrict__ qkv,
                                                     u16* __restrict__ vt) {
    __shared__ u16 tile[64][66];
    int st = blockIdx.x & 31;
    int bh = blockIdx.x >> 5;
    int b = bh >> 4, h = bh & 15;
    int s0 = st * 64;
    int t = threadIdx.x;
#pragma unroll
    for (int it = 0; it < 16; ++it) {
        int idx = it * 256 + t;
        int sr = idx >> 6, c = idx & 63;
        tile[sr][c] = qkv[(size_t)(b * 2048 + s0 + sr) * 3072 + 2048 + h * 64 + c];
    }
    __syncthreads();
#pragma unroll
    for (int it = 0; it < 16; ++it) {
        int idx = it * 256 + t;
        int hd = idx >> 6, sc = idx & 63;
        vt[((size_t)(bh * 64 + hd)) * 2048 + s0 + sc] = tile[sc][hd];
    }
}

// ---------------- flash attention (round-7 proven) ---------------------------------
// 512-thread block (8 waves), balanced causal pairing: block j owns q-tiles {j,31-j}.
// Wave-group k-parity split: waves 0-3 process even k-tiles, waves 4-7 odd k-tiles;
// fixed-max softmax => group partials (numerator, l) are additive, merged through
// LDS at the end. Per-wave: swapped QK^T, lane-local softmax, exp2-folded decay,
// cvt_pk pack, LDS-staged K/V (both-sides XOR swizzle), per-group double-buffer,
// counted vmcnt. LDS 80KB -> 2 blocks/CU = 16 waves/CU.

__device__ __forceinline__ void attn_tile(const u16* __restrict__ Ks,
                                          const u16* __restrict__ Vs,
                                          u16* __restrict__ Pw,
                                          const int* __restrict__ dbk,
                                          bf16x8 bq0, bf16x8 bq1, float dq_c, float c1,
                                          int qrel, bool domask,
                                          float& l_part, f32x4* acc, int lr, int lg) {
    f32x4 st_acc[4];
    __builtin_amdgcn_s_setprio(1);
#pragma unroll
    for (int st = 0; st < 4; ++st) {
        const int r2 = st * 16 + lr;
        const u16* kr = Ks + r2 * 64;
        bf16x8 ka0 = *(const bf16x8*)(kr + ((lg ^ (r2 & 7)) << 3));
        bf16x8 ka1 = *(const bf16x8*)(kr + (((4 + lg) ^ (r2 & 7)) << 3));
        f32x4 t = {};
        t = __builtin_amdgcn_mfma_f32_16x16x32_bf16(ka0, bq0, t, 0, 0, 0);
        t = __builtin_amdgcn_mfma_f32_16x16x32_bf16(ka1, bq1, t, 0, 0, 0);
        st_acc[st] = t;
    }
    __builtin_amdgcn_s_setprio(0);
    const float L2E = 1.4426950408889634f;
    const float POFF = 17.312340490667562f;  // 12*log2(e)
    float p[4][4];
#pragma unroll
    for (int st = 0; st < 4; ++st) {
        int4 dk4 = *(const int4*)(dbk + st * 16 + lg * 4);
#pragma unroll
        for (int r = 0; r < 4; ++r) {
            float dkf = (float)((&dk4.x)[r]);
            float dec = exp2f(__builtin_fmaf(dkf, c1, -dq_c));  // decay/8
            float v = st_acc[st][r] * dec;
            p[st][r] = exp2f(__builtin_fmaf(v, L2E, -POFF));
        }
    }
    if (domask) {
#pragma unroll
        for (int st = 0; st < 4; ++st)
#pragma unroll
            for (int r = 0; r < 4; ++r)
                p[st][r] = (st * 16 + lg * 4 + r <= qrel) ? p[st][r] : 0.f;
    }
#pragma unroll
    for (int st = 0; st < 4; ++st)
#pragma unroll
        for (int r = 0; r < 4; ++r) l_part += p[st][r];
#pragma unroll
    for (int st = 0; st < 4; ++st) {
        unsigned lo, hi;
        asm("v_cvt_pk_bf16_f32 %0, %1, %2" : "=v"(lo) : "v"(p[st][0]), "v"(p[st][1]));
        asm("v_cvt_pk_bf16_f32 %0, %1, %2" : "=v"(hi) : "v"(p[st][2]), "v"(p[st][3]));
        uint2 pk;
        pk.x = lo;
        pk.y = hi;
        int chunk = st * 2 + (lg >> 1);
        int idx = lr * 64 + ((chunk ^ (lr & 7)) << 3) + ((lg & 1) << 2);
        *(uint2*)&Pw[idx] = pk;
    }
    __builtin_amdgcn_s_setprio(1);
#pragma unroll
    for (int pv = 0; pv < 2; ++pv) {
        int chunk = pv * 4 + lg;
        bf16x8 pa = *(const bf16x8*)&Pw[lr * 64 + ((chunk ^ (lr & 7)) << 3)];
#pragma unroll
        for (int c = 0; c < 4; ++c) {
            const int r3 = c * 16 + lr;
            bf16x8 bv = *(const bf16x8*)(Vs + r3 * 64 + ((chunk ^ (r3 & 7)) << 3));
            acc[c] = __builtin_amdgcn_mfma_f32_16x16x32_bf16(pa, bv, acc[c], 0, 0, 0);
        }
    }
    __builtin_amdgcn_s_setprio(0);
}

__global__ __launch_bounds__(512, 4) void attn_k(const u16* __restrict__ qkv,
                                                 const u16* __restrict__ vt,
                                                 const int* __restrict__ days,
                                                 const float* __restrict__ decay_p,
                                                 u16* __restrict__ attn_out) {
    __shared__ __align__(16) u16 Ks[4][4096];   // 4 tile-slots: (pair-parity)*2 + group
    __shared__ __align__(16) u16 Vs[4][4096];
    __shared__ __align__(16) u16 Plds[8][1024];
    const int tid = threadIdx.x;
    const int lane = tid & 63;
    const int w = tid >> 6;      // 0..7
    const int qw = w & 3;        // q-row subtile within the 64-row q-tiles
    const int g = w >> 2;        // k-parity group
    const int lr = lane & 15, lg = lane >> 4;
    // bijective XCD swizzle (512 = 8 XCDs x 64): consecutive bh share an XCD's L2
    const int wg = (blockIdx.x & 7) * 64 + (blockIdx.x >> 3);
    const int j = wg & 15;
    const int bh = wg >> 4;
    const int b = bh >> 4, h = bh & 15;
    const int qtB = 31 - j;
    const int qbA = j * 64 + qw * 16;
    const int qbB = qtB * 64 + qw * 16;
    const float rate = decay_p[0];
    const float c1 = rate * 1.4426950408889634f;

    const u16* qmat = qkv + (size_t)b * 2048 * 3072 + h * 64;
    const u16* kmat = qmat + 1024;
    const u16* vtm = vt + (size_t)bh * 64 * 2048;
    const int* db = days + b * 2048;

    // staging: group's 4 waves (qw=0..3) cover the 512 16B-chunks of one tile.
    // LDS dest linear; global source pre-applies the read-side XOR swizzle.
    const int cp0 = (qw * 2 + 0) * 64 + lane;
    const int cp1 = (qw * 2 + 1) * 64 + lane;
    const int r0 = cp0 >> 3, c0 = cp0 & 7;
    const int r1 = cp1 >> 3, c1i = cp1 & 7;
    const u16* ksrc0 = kmat + (size_t)r0 * 3072 + ((c0 ^ (r0 & 7)) << 3);
    const u16* ksrc1 = kmat + (size_t)r1 * 3072 + ((c1i ^ (r1 & 7)) << 3);
    const u16* vsrc0 = vtm + (size_t)r0 * 2048 + ((c0 ^ (r0 & 7)) << 3);
    const u16* vsrc1 = vtm + (size_t)r1 * 2048 + ((c1i ^ (r1 & 7)) << 3);
    const int doff0 = (qw * 2 + 0) * 512;
    const int doff1 = (qw * 2 + 1) * 512;

#define STAGE(T, SLOT)                                                                 \
    do {                                                                               \
        __builtin_amdgcn_global_load_lds(                                              \
            (const __attribute__((address_space(1))) void*)(ksrc0 +                    \
                                                            (size_t)(T) * 64 * 3072), \
            (__attribute__((address_space(3))) void*)(&Ks[SLOT][doff0]), 16, 0, 0);    \
        __builtin_amdgcn_global_load_lds(                                              \
            (const __attribute__((address_space(1))) void*)(ksrc1 +                    \
                                                            (size_t)(T) * 64 * 3072), \
            (__attribute__((address_space(3))) void*)(&Ks[SLOT][doff1]), 16, 0, 0);    \
        __builtin_amdgcn_global_load_lds(                                              \
            (const __attribute__((address_space(1))) void*)(vsrc0 + (size_t)(T) * 64), \
            (__attribute__((address_space(3))) void*)(&Vs[SLOT][doff0]), 16, 0, 0);    \
        __builtin_amdgcn_global_load_lds(                                              \
            (const __attribute__((address_space(1))) void*)(vsrc1 + (size_t)(T) * 64), \
            (__attribute__((address_space(3))) void*)(&Vs[SLOT][doff1]), 16, 0, 0);    \
    } while (0)

    STAGE(g, g);  // pair 0: group g stages tile g into slot g

    bf16x8 bqA0, bqA1, bqB0, bqB1;
    {
        const u16* qpA = qmat + (size_t)(qbA + lr) * 3072 + lg * 8;
        bqA0 = *(const bf16x8*)qpA;
        bqA1 = *(const bf16x8*)(qpA + 32);
        const u16* qpB = qmat + (size_t)(qbB + lr) * 3072 + lg * 8;
        bqB0 = *(const bf16x8*)qpB;
        bqB1 = *(const bf16x8*)(qpB + 32);
    }
    // dq_c = (dq*rate + ln8)*log2e = dq*c1 + 3
    const float dq_cA = (float)db[qbA + lr] * c1 + 3.0f;
    const float dq_cB = (float)db[qbB + lr] * c1 + 3.0f;

    float lA = 0.f, lB = 0.f;
    f32x4 accA[4] = {};
    f32x4 accB[4] = {};

    const int nkt = (33 - j) >> 1;  // ceil((32-j)/2) tile-pairs
    for (int it = 0; it < nkt; ++it) {
        const int kt = 2 * it + g;
        const int cur = ((it & 1) << 1) + g;
        if (it + 1 < nkt) {
            STAGE(2 * (it + 1) + g, (((it + 1) & 1) << 1) + g);
            asm volatile("s_waitcnt vmcnt(4)" ::: "memory");
        } else {
            asm volatile("s_waitcnt vmcnt(0)" ::: "memory");
        }
        __builtin_amdgcn_s_barrier();
        const int* dbk = db + kt * 64;
        if (kt <= qtB)
            attn_tile(Ks[cur], Vs[cur], Plds[w], dbk, bqB0, bqB1, dq_cB, c1,
                      qw * 16 + lr, kt == qtB, lB, accB, lr, lg);
        if (kt <= j)
            attn_tile(Ks[cur], Vs[cur], Plds[w], dbk, bqA0, bqA1, dq_cA, c1,
                      qw * 16 + lr, kt == j, lA, accA, lr, lg);
        __builtin_amdgcn_s_barrier();
    }
#undef STAGE

    // merge group partials through LDS, then group 0 writes output
    float* xch = (float*)&Plds[0][0];  // 4096 floats = 4 qw-regions x 64 lanes x 16
    float* lx = (float*)&Ks[0][0];     // l exchange
#pragma unroll
    for (int t = 0; t < 2; ++t) {
        float lp = t ? lA : lB;
        f32x4* acc = t ? accA : accB;
        const int qt = t ? j : qtB;
        __syncthreads();
        if (g == 1) {
            float* dst = xch + qw * 1024 + lane * 16;
#pragma unroll
            for (int c = 0; c < 4; ++c) *(f32x4*)(dst + c * 4) = acc[c];
            lx[qw * 64 + lane] = lp;
        }
        __syncthreads();
        if (g == 0) {
            const float* src = xch + qw * 1024 + lane * 16;
#pragma unroll
            for (int c = 0; c < 4; ++c) acc[c] += *(const f32x4*)(src + c * 4);
            lp += lx[qw * 64 + lane];
            float l_full = lp + __shfl_xor(lp, 16);
            l_full += __shfl_xor(l_full, 32);
            float inv_[4];
#pragma unroll
            for (int r = 0; r < 4; ++r) inv_[r] = 1.0f / __shfl(l_full, lg * 4 + r);
#pragma unroll
            for (int c = 0; c < 4; ++c)
#pragma unroll
                for (int r = 0; r < 4; ++r) {
                    const int qg = qt * 64 + qw * 16 + lg * 4 + r;
                    attn_out[(size_t)(b * 2048 + qg) * 1024 + h * 64 + c * 16 + lr] =
                        f2bf(acc[c][r] * inv_[r]);
                }
        }
    }
}

// ---------------- launch -----------------------------------------------------------
extern "C" void kernel_launch(void* const* d_in, const int* in_sizes, int n_in,
                              void* d_out, int out_size, void* d_ws, size_t ws_size,
                              hipStream_t stream) {
    const float* x = (const float*)d_in[0];
    const float* Wq = (const float*)d_in[1];
    const float* bq = (const float*)d_in[2];
    const float* Wk = (const float*)d_in[3];
    const float* bk = (const float*)d_in[4];
    const float* Wv = (const float*)d_in[5];
    const float* bv = (const float*)d_in[6];
    const float* Wo = (const float*)d_in[7];
    const float* bo = (const float*)d_in[8];
    const float* decay = (const float*)d_in[9];
    const int* days = (const int*)d_in[11];
    float* out = (float*)d_out;

    char* ws = (char*)d_ws;
    u16* xb = (u16*)(ws);                   //  8 MB: x bf16 [4096][1024]
    u16* wqkv = (u16*)(ws + 8388608);       //  6 MB: [Wq;Wk;Wv] bf16 [3072][1024]
    u16* wo = (u16*)(ws + 14680064);        //  2 MB: Wo bf16 [1024][1024]
    u16* qkvb = (u16*)(ws + 16777216);      // 24 MB: qkv bf16 [4096][3072]
    u16* vtb = (u16*)(ws + 41943040);       //  8 MB: Vt bf16 [32][64][2048]
    u16* attb = (u16*)(ws + 50331648);      //  8 MB: attn out bf16 [4096][1024]

    convert_all_k<<<8192, 256, 0, stream>>>(x, Wq, Wk, Wv, Wo, xb, wqkv, wo);

    gemm_bt<0><<<768, 256, 0, stream>>>(xb, wqkv, bq, bk, bv, days, qkvb, nullptr,
                                        4096, 3072, 1024);
    v_transpose_k<<<1024, 256, 0, stream>>>(qkvb, vtb);
    attn_k<<<512, 512, 0, stream>>>(qkvb, vtb, days, decay, attb);
    gemm_bt<1><<<256, 256, 0, stream>>>(attb, wo, bo, nullptr, nullptr, days, nullptr,
                                        out, 4096, 1024, 1024);
}

// Round 11
// 118.630 us; speedup vs baseline: 1.4478x; 1.2550x over previous
//
#include <hip/hip_runtime.h>
#include <hip/hip_bf16.h>

// B=2, S=2048, D=1024, H=16, HD=64. fp32 in, fp32 out, bf16-tolerance threshold.
// Pipeline: convert->bf16 (merged) | QKV GEMM (fused bias+RoPE) | V-transpose |
//           flash attn (r7 structure + distant-tile fast path) | out GEMM.

typedef unsigned short u16;
typedef short bf16x8 __attribute__((ext_vector_type(8)));
typedef float f32x4 __attribute__((ext_vector_type(4)));

__device__ __forceinline__ u16 f2bf(float f) {
    unsigned u = __builtin_bit_cast(unsigned, f);
    u += 0x7fffu + ((u >> 16) & 1u);   // RNE
    return (u16)(u >> 16);
}
__device__ __forceinline__ float bf2f(u16 h) {
    unsigned u = ((unsigned)h) << 16;
    return __builtin_bit_cast(float, u);
}

// ---------------- fused fp32 -> bf16 convert for all 5 tensors ---------------------
__global__ __launch_bounds__(256) void convert_all_k(const float* __restrict__ x,
                                                     const float* __restrict__ wq,
                                                     const float* __restrict__ wk,
                                                     const float* __restrict__ wv,
                                                     const float* __restrict__ wo_,
                                                     u16* __restrict__ xb,
                                                     u16* __restrict__ wqkv,
                                                     u16* __restrict__ wob) {
    int i = (blockIdx.x * 256 + threadIdx.x) * 4;
    const float* src;
    u16* dst;
    int off;
    if (i < 4194304) {
        src = x; dst = xb; off = i;
    } else if (i < 5242880) {
        src = wq; dst = wqkv; off = i - 4194304;
    } else if (i < 6291456) {
        src = wk; dst = wqkv + 1048576; off = i - 5242880;
    } else if (i < 7340032) {
        src = wv; dst = wqkv + 2097152; off = i - 6291456;
    } else {
        src = wo_; dst = wob; off = i - 7340032;
    }
    float4 v = *(const float4*)(src + off);
    uint2 o;
    o.x = (unsigned)f2bf(v.x) | ((unsigned)f2bf(v.y) << 16);
    o.y = (unsigned)f2bf(v.z) | ((unsigned)f2bf(v.w) << 16);
    *(uint2*)(dst + off) = o;
}

// ---------------- bf16 GEMM: C[m][n] = sum_k A[m][k]*Bw[n][k] ----------------------
// EPI==0: bf16 out, 3-segment bias (bq|bk|bv), fused RoPE on cols < 2048.
// EPI==1: fp32 out, bias0 only, no RoPE.
template <int EPI>
__global__ __launch_bounds__(256) void gemm_bt(const u16* __restrict__ A,
                                               const u16* __restrict__ Bw,
                                               const float* __restrict__ bias0,
                                               const float* __restrict__ bias1,
                                               const float* __restrict__ bias2,
                                               const int* __restrict__ days,
                                               u16* __restrict__ outB,
                                               float* __restrict__ outF,
                                               int M, int N, int K) {
    __shared__ __align__(16) u16 As[128 * 32];
    __shared__ __align__(16) u16 Bs[128 * 32];
    const int tid = threadIdx.x;
    const int lane = tid & 63;
    const int w = tid >> 6;
    const int wr = w >> 1, wc = w & 1;
    const int lr = lane & 15, lg = lane >> 4;
    const int nbn = N >> 7;
    const int m0 = (blockIdx.x / nbn) << 7;
    const int n0 = (blockIdx.x % nbn) << 7;

    f32x4 acc[4][4] = {};

    const u16* aptr[2];
    const u16* bptr[2];
    int ldsoff[2];
#pragma unroll
    for (int i = 0; i < 2; ++i) {
        int c = (w * 2 + i) * 64 + lane;
        int row = c >> 2, kc = (c & 3) << 3;
        aptr[i] = A + (size_t)(m0 + row) * K + kc;
        bptr[i] = Bw + (size_t)(n0 + row) * K + kc;
        ldsoff[i] = (w * 2 + i) * 512;
    }

    for (int k0 = 0; k0 < K; k0 += 32) {
#pragma unroll
        for (int i = 0; i < 2; ++i) {
            __builtin_amdgcn_global_load_lds(
                (const __attribute__((address_space(1))) void*)(aptr[i] + k0),
                (__attribute__((address_space(3))) void*)(As + ldsoff[i]), 16, 0, 0);
            __builtin_amdgcn_global_load_lds(
                (const __attribute__((address_space(1))) void*)(bptr[i] + k0),
                (__attribute__((address_space(3))) void*)(Bs + ldsoff[i]), 16, 0, 0);
        }
        __syncthreads();
        bf16x8 af[4], bfr[4];
#pragma unroll
        for (int i = 0; i < 4; ++i)
            af[i] = *(const bf16x8*)(As + (wr * 64 + i * 16 + lr) * 32 + lg * 8);
#pragma unroll
        for (int j = 0; j < 4; ++j)
            bfr[j] = *(const bf16x8*)(Bs + (wc * 64 + j * 16 + lr) * 32 + lg * 8);
#pragma unroll
        for (int i = 0; i < 4; ++i)
#pragma unroll
            for (int j = 0; j < 4; ++j)
                acc[i][j] = __builtin_amdgcn_mfma_f32_16x16x32_bf16(af[i], bfr[j],
                                                                    acc[i][j], 0, 0, 0);
        __syncthreads();
    }

    auto bsel = [&](int ng) -> float {
        if (EPI != 0) return bias0[ng];
        return (ng < 1024) ? bias0[ng] : (ng < 2048) ? bias1[ng - 1024] : bias2[ng - 2048];
    };

    if (EPI == 0 && (n0 + wc * 64) < 2048) {
        // q/k region: wave's 64 cols = one full head; pairs (j, j+2) hold (x1, x2).
        const float C1 = -0.41524101186091903f;  // -log2(10000)/32
        const float inv0 = exp2f((float)lr * C1);
        const float inv1 = exp2f((float)(16 + lr) * C1);
#pragma unroll
        for (int i = 0; i < 4; ++i) {
            int mg = m0 + wr * 64 + i * 16 + lg * 4;
#pragma unroll
            for (int r = 0; r < 4; ++r) {
                int m = mg + r;
                int d = days[m];
                int ad = d < 0 ? -d : d;
                ad = ad > 2047 ? 2047 : ad;
                float pos = (float)ad;
#pragma unroll
                for (int j = 0; j < 2; ++j) {
                    int ng1 = n0 + wc * 64 + j * 16 + lr;
                    int ng2 = ng1 + 32;
                    float x1 = acc[i][j][r] + bsel(ng1);
                    float x2 = acc[i][j + 2][r] + bsel(ng2);
                    float ang = pos * (j ? inv1 : inv0);
                    float sn, cs;
                    __sincosf(ang, &sn, &cs);
                    outB[(size_t)m * N + ng1] = f2bf(x1 * cs - x2 * sn);
                    outB[(size_t)m * N + ng2] = f2bf(x2 * cs + x1 * sn);
                }
            }
        }
    } else {
#pragma unroll
        for (int i = 0; i < 4; ++i) {
            int mg = m0 + wr * 64 + i * 16 + lg * 4;
#pragma unroll
            for (int j = 0; j < 4; ++j) {
                int ng = n0 + wc * 64 + j * 16 + lr;
                float bias = bsel(ng);
#pragma unroll
                for (int r = 0; r < 4; ++r) {
                    float v = acc[i][j][r] + bias;
                    if (EPI == 0)
                        outB[(size_t)(mg + r) * N + ng] = f2bf(v);
                    else
                        outF[(size_t)(mg + r) * N + ng] = v;
                }
            }
        }
    }
}

// ---------------- V transpose: qkv v-region -> Vt[b,h,hd,s] ------------------------
__global__ __launch_bounds__(256) void v_transpose_k(const u16* __restrict__ qkv,
                                                     u16* __restrict__ vt) {
    __shared__ u16 tile[64][66];
    int st = blockIdx.x & 31;
    int bh = blockIdx.x >> 5;
    int b = bh >> 4, h = bh & 15;
    int s0 = st * 64;
    int t = threadIdx.x;
#pragma unroll
    for (int it = 0; it < 16; ++it) {
        int idx = it * 256 + t;
        int sr = idx >> 6, c = idx & 63;
        tile[sr][c] = qkv[(size_t)(b * 2048 + s0 + sr) * 3072 + 2048 + h * 64 + c];
    }
    __syncthreads();
#pragma unroll
    for (int it = 0; it < 16; ++it) {
        int idx = it * 256 + t;
        int hd = idx >> 6, sc = idx & 63;
        vt[((size_t)(bh * 64 + hd)) * 2048 + s0 + sc] = tile[sc][hd];
    }
}

// ---------------- flash attention (r7 structure + distant-tile fast path) ----------
// 512-thread block (8 waves), balanced causal pairing {j, 31-j}, wave-group k-parity
// split, fixed-max softmax (p = exp(v - 12), v = s*decay). NEW: when the whole tile
// has dec = exp2(dk*c1 - dq_c) < 2^-20 (wave-uniform __all on dkmax), then
// |v| < 2^-14 and p == e^-12 to below-bf16 precision -> skip QK^T, exps, mask and
// pack; PV with a constant e^-12 A-fragment; l += 16*e^-12. ~80% of causal tiles
// (days sorted ~1/pos) take this path. Exact path is byte-identical to round 7.

__device__ __forceinline__ void attn_tile(const u16* __restrict__ Ks,
                                          const u16* __restrict__ Vs,
                                          u16* __restrict__ Pw,
                                          const int* __restrict__ dbk,
                                          float dkmax_c, bf16x8 pconst, float pcr,
                                          bf16x8 bq0, bf16x8 bq1, float dq_c, float c1,
                                          int qrel, bool domask,
                                          float& l_part, f32x4* acc, int lr, int lg) {
    if (!domask && __all(dkmax_c - dq_c < -20.0f)) {
        // distant tile: every p equals e^-12 (rel. err < 2^-14, below bf16 eps)
        l_part += 16.0f * pcr;
        __builtin_amdgcn_s_setprio(1);
#pragma unroll
        for (int pv = 0; pv < 2; ++pv) {
            int chunk = pv * 4 + lg;
#pragma unroll
            for (int c = 0; c < 4; ++c) {
                const int r3 = c * 16 + lr;
                bf16x8 bv = *(const bf16x8*)(Vs + r3 * 64 + ((chunk ^ (r3 & 7)) << 3));
                acc[c] = __builtin_amdgcn_mfma_f32_16x16x32_bf16(pconst, bv, acc[c], 0, 0, 0);
            }
        }
        __builtin_amdgcn_s_setprio(0);
        return;
    }
    f32x4 st_acc[4];
    __builtin_amdgcn_s_setprio(1);
#pragma unroll
    for (int st = 0; st < 4; ++st) {
        const int r2 = st * 16 + lr;
        const u16* kr = Ks + r2 * 64;
        bf16x8 ka0 = *(const bf16x8*)(kr + ((lg ^ (r2 & 7)) << 3));
        bf16x8 ka1 = *(const bf16x8*)(kr + (((4 + lg) ^ (r2 & 7)) << 3));
        f32x4 t = {};
        t = __builtin_amdgcn_mfma_f32_16x16x32_bf16(ka0, bq0, t, 0, 0, 0);
        t = __builtin_amdgcn_mfma_f32_16x16x32_bf16(ka1, bq1, t, 0, 0, 0);
        st_acc[st] = t;
    }
    __builtin_amdgcn_s_setprio(0);
    const float L2E = 1.4426950408889634f;
    const float POFF = 17.312340490667562f;  // 12*log2(e)
    float p[4][4];
#pragma unroll
    for (int st = 0; st < 4; ++st) {
        int4 dk4 = *(const int4*)(dbk + st * 16 + lg * 4);
#pragma unroll
        for (int r = 0; r < 4; ++r) {
            float dkf = (float)((&dk4.x)[r]);
            float dec = exp2f(__builtin_fmaf(dkf, c1, -dq_c));  // decay/8
            float v = st_acc[st][r] * dec;
            p[st][r] = exp2f(__builtin_fmaf(v, L2E, -POFF));
        }
    }
    if (domask) {
#pragma unroll
        for (int st = 0; st < 4; ++st)
#pragma unroll
            for (int r = 0; r < 4; ++r)
                p[st][r] = (st * 16 + lg * 4 + r <= qrel) ? p[st][r] : 0.f;
    }
#pragma unroll
    for (int st = 0; st < 4; ++st)
#pragma unroll
        for (int r = 0; r < 4; ++r) l_part += p[st][r];
#pragma unroll
    for (int st = 0; st < 4; ++st) {
        unsigned lo, hi;
        asm("v_cvt_pk_bf16_f32 %0, %1, %2" : "=v"(lo) : "v"(p[st][0]), "v"(p[st][1]));
        asm("v_cvt_pk_bf16_f32 %0, %1, %2" : "=v"(hi) : "v"(p[st][2]), "v"(p[st][3]));
        uint2 pk;
        pk.x = lo;
        pk.y = hi;
        int chunk = st * 2 + (lg >> 1);
        int idx = lr * 64 + ((chunk ^ (lr & 7)) << 3) + ((lg & 1) << 2);
        *(uint2*)&Pw[idx] = pk;
    }
    __builtin_amdgcn_s_setprio(1);
#pragma unroll
    for (int pv = 0; pv < 2; ++pv) {
        int chunk = pv * 4 + lg;
        bf16x8 pa = *(const bf16x8*)&Pw[lr * 64 + ((chunk ^ (lr & 7)) << 3)];
#pragma unroll
        for (int c = 0; c < 4; ++c) {
            const int r3 = c * 16 + lr;
            bf16x8 bv = *(const bf16x8*)(Vs + r3 * 64 + ((chunk ^ (r3 & 7)) << 3));
            acc[c] = __builtin_amdgcn_mfma_f32_16x16x32_bf16(pa, bv, acc[c], 0, 0, 0);
        }
    }
    __builtin_amdgcn_s_setprio(0);
}

__global__ __launch_bounds__(512, 4) void attn_k(const u16* __restrict__ qkv,
                                                 const u16* __restrict__ vt,
                                                 const int* __restrict__ days,
                                                 const float* __restrict__ decay_p,
                                                 u16* __restrict__ attn_out) {
    __shared__ __align__(16) u16 Ks[4][4096];   // 4 tile-slots: (pair-parity)*2 + group
    __shared__ __align__(16) u16 Vs[4][4096];
    __shared__ __align__(16) u16 Plds[8][1024];
    const int tid = threadIdx.x;
    const int lane = tid & 63;
    const int w = tid >> 6;      // 0..7
    const int qw = w & 3;        // q-row subtile within the 64-row q-tiles
    const int g = w >> 2;        // k-parity group
    const int lr = lane & 15, lg = lane >> 4;
    // bijective XCD swizzle (512 = 8 XCDs x 64): consecutive bh share an XCD's L2
    const int wg = (blockIdx.x & 7) * 64 + (blockIdx.x >> 3);
    const int j = wg & 15;
    const int bh = wg >> 4;
    const int b = bh >> 4, h = bh & 15;
    const int qtB = 31 - j;
    const int qbA = j * 64 + qw * 16;
    const int qbB = qtB * 64 + qw * 16;
    const float rate = decay_p[0];
    const float c1 = rate * 1.4426950408889634f;

    const u16* qmat = qkv + (size_t)b * 2048 * 3072 + h * 64;
    const u16* kmat = qmat + 1024;
    const u16* vtm = vt + (size_t)bh * 64 * 2048;
    const int* db = days + b * 2048;

    // staging: group's 4 waves (qw=0..3) cover the 512 16B-chunks of one tile.
    // LDS dest linear; global source pre-applies the read-side XOR swizzle.
    const int cp0 = (qw * 2 + 0) * 64 + lane;
    const int cp1 = (qw * 2 + 1) * 64 + lane;
    const int r0 = cp0 >> 3, c0 = cp0 & 7;
    const int r1 = cp1 >> 3, c1i = cp1 & 7;
    const u16* ksrc0 = kmat + (size_t)r0 * 3072 + ((c0 ^ (r0 & 7)) << 3);
    const u16* ksrc1 = kmat + (size_t)r1 * 3072 + ((c1i ^ (r1 & 7)) << 3);
    const u16* vsrc0 = vtm + (size_t)r0 * 2048 + ((c0 ^ (r0 & 7)) << 3);
    const u16* vsrc1 = vtm + (size_t)r1 * 2048 + ((c1i ^ (r1 & 7)) << 3);
    const int doff0 = (qw * 2 + 0) * 512;
    const int doff1 = (qw * 2 + 1) * 512;

#define STAGE(T, SLOT)                                                                 \
    do {                                                                               \
        __builtin_amdgcn_global_load_lds(                                              \
            (const __attribute__((address_space(1))) void*)(ksrc0 +                    \
                                                            (size_t)(T) * 64 * 3072), \
            (__attribute__((address_space(3))) void*)(&Ks[SLOT][doff0]), 16, 0, 0);    \
        __builtin_amdgcn_global_load_lds(                                              \
            (const __attribute__((address_space(1))) void*)(ksrc1 +                    \
                                                            (size_t)(T) * 64 * 3072), \
            (__attribute__((address_space(3))) void*)(&Ks[SLOT][doff1]), 16, 0, 0);    \
        __builtin_amdgcn_global_load_lds(                                              \
            (const __attribute__((address_space(1))) void*)(vsrc0 + (size_t)(T) * 64), \
            (__attribute__((address_space(3))) void*)(&Vs[SLOT][doff0]), 16, 0, 0);    \
        __builtin_amdgcn_global_load_lds(                                              \
            (const __attribute__((address_space(1))) void*)(vsrc1 + (size_t)(T) * 64), \
            (__attribute__((address_space(3))) void*)(&Vs[SLOT][doff1]), 16, 0, 0);    \
    } while (0)

    STAGE(g, g);  // pair 0: group g stages tile g into slot g

    bf16x8 bqA0, bqA1, bqB0, bqB1;
    {
        const u16* qpA = qmat + (size_t)(qbA + lr) * 3072 + lg * 8;
        bqA0 = *(const bf16x8*)qpA;
        bqA1 = *(const bf16x8*)(qpA + 32);
        const u16* qpB = qmat + (size_t)(qbB + lr) * 3072 + lg * 8;
        bqB0 = *(const bf16x8*)qpB;
        bqB1 = *(const bf16x8*)(qpB + 32);
    }
    // dq_c = (dq*rate + ln8)*log2e = dq*c1 + 3
    const float dq_cA = (float)db[qbA + lr] * c1 + 3.0f;
    const float dq_cB = (float)db[qbB + lr] * c1 + 3.0f;

    // constant P value for distant tiles: e^-12 (bf16-rounded, used for PV and l)
    const u16 pcu = f2bf(exp2f(-17.312340490667562f));
    const float pcr = bf2f(pcu);
    bf16x8 pconst;
#pragma unroll
    for (int i = 0; i < 8; ++i) pconst[i] = (short)pcu;

    float lA = 0.f, lB = 0.f;
    f32x4 accA[4] = {};
    f32x4 accB[4] = {};

    const int nkt = (33 - j) >> 1;  // ceil((32-j)/2) tile-pairs
    for (int it = 0; it < nkt; ++it) {
        const int kt = 2 * it + g;
        const int cur = ((it & 1) << 1) + g;
        if (it + 1 < nkt) {
            STAGE(2 * (it + 1) + g, (((it + 1) & 1) << 1) + g);
            asm volatile("s_waitcnt vmcnt(4)" ::: "memory");
        } else {
            asm volatile("s_waitcnt vmcnt(0)" ::: "memory");
        }
        __builtin_amdgcn_s_barrier();
        const int* dbk = db + kt * 64;
        const float dkmax_c = (float)dbk[63] * c1;  // sorted -> tile max
        if (kt <= qtB)
            attn_tile(Ks[cur], Vs[cur], Plds[w], dbk, dkmax_c, pconst, pcr,
                      bqB0, bqB1, dq_cB, c1, qw * 16 + lr, kt == qtB, lB, accB, lr, lg);
        if (kt <= j)
            attn_tile(Ks[cur], Vs[cur], Plds[w], dbk, dkmax_c, pconst, pcr,
                      bqA0, bqA1, dq_cA, c1, qw * 16 + lr, kt == j, lA, accA, lr, lg);
        __builtin_amdgcn_s_barrier();
    }
#undef STAGE

    // merge group partials through LDS, then group 0 writes output
    float* xch = (float*)&Plds[0][0];  // 4096 floats = 4 qw-regions x 64 lanes x 16
    float* lx = (float*)&Ks[0][0];     // l exchange
#pragma unroll
    for (int t = 0; t < 2; ++t) {
        float lp = t ? lA : lB;
        f32x4* acc = t ? accA : accB;
        const int qt = t ? j : qtB;
        __syncthreads();
        if (g == 1) {
            float* dst = xch + qw * 1024 + lane * 16;
#pragma unroll
            for (int c = 0; c < 4; ++c) *(f32x4*)(dst + c * 4) = acc[c];
            lx[qw * 64 + lane] = lp;
        }
        __syncthreads();
        if (g == 0) {
            const float* src = xch + qw * 1024 + lane * 16;
#pragma unroll
            for (int c = 0; c < 4; ++c) acc[c] += *(const f32x4*)(src + c * 4);
            lp += lx[qw * 64 + lane];
            float l_full = lp + __shfl_xor(lp, 16);
            l_full += __shfl_xor(l_full, 32);
            float inv_[4];
#pragma unroll
            for (int r = 0; r < 4; ++r) inv_[r] = 1.0f / __shfl(l_full, lg * 4 + r);
#pragma unroll
            for (int c = 0; c < 4; ++c)
#pragma unroll
                for (int r = 0; r < 4; ++r) {
                    const int qg = qt * 64 + qw * 16 + lg * 4 + r;
                    attn_out[(size_t)(b * 2048 + qg) * 1024 + h * 64 + c * 16 + lr] =
                        f2bf(acc[c][r] * inv_[r]);
                }
        }
    }
}

// ---------------- launch -----------------------------------------------------------
extern "C" void kernel_launch(void* const* d_in, const int* in_sizes, int n_in,
                              void* d_out, int out_size, void* d_ws, size_t ws_size,
                              hipStream_t stream) {
    const float* x = (const float*)d_in[0];
    const float* Wq = (const float*)d_in[1];
    const float* bq = (const float*)d_in[2];
    const float* Wk = (const float*)d_in[3];
    const float* bk = (const float*)d_in[4];
    const float* Wv = (const float*)d_in[5];
    const float* bv = (const float*)d_in[6];
    const float* Wo = (const float*)d_in[7];
    const float* bo = (const float*)d_in[8];
    const float* decay = (const float*)d_in[9];
    const int* days = (const int*)d_in[11];
    float* out = (float*)d_out;

    char* ws = (char*)d_ws;
    u16* xb = (u16*)(ws);                   //  8 MB: x bf16 [4096][1024]
    u16* wqkv = (u16*)(ws + 8388608);       //  6 MB: [Wq;Wk;Wv] bf16 [3072][1024]
    u16* wo = (u16*)(ws + 14680064);        //  2 MB: Wo bf16 [1024][1024]
    u16* qkvb = (u16*)(ws + 16777216);      // 24 MB: qkv bf16 [4096][3072]
    u16* vtb = (u16*)(ws + 41943040);       //  8 MB: Vt bf16 [32][64][2048]
    u16* attb = (u16*)(ws + 50331648);      //  8 MB: attn out bf16 [4096][1024]

    convert_all_k<<<8192, 256, 0, stream>>>(x, Wq, Wk, Wv, Wo, xb, wqkv, wo);

    gemm_bt<0><<<768, 256, 0, stream>>>(xb, wqkv, bq, bk, bv, days, qkvb, nullptr,
                                        4096, 3072, 1024);
    v_transpose_k<<<1024, 256, 0, stream>>>(qkvb, vtb);
    attn_k<<<512, 512, 0, stream>>>(qkvb, vtb, days, decay, attb);
    gemm_bt<1><<<256, 256, 0, stream>>>(attb, wo, bo, nullptr, nullptr, days, nullptr,
                                        out, 4096, 1024, 1024);
}

// Round 12
// 111.488 us; speedup vs baseline: 1.5406x; 1.0641x over previous
//
#include <hip/hip_runtime.h>
#include <hip/hip_bf16.h>

// B=2, S=2048, D=1024, H=16, HD=64. fp32 in, fp32 out, bf16-tolerance threshold.
// Pipeline: convert->bf16 (merged) | QKV GEMM (fused bias+RoPE, dbuf+counted vmcnt) |
//           V-transpose | flash attn (r7 structure + distant-tile fast path) | out GEMM.

typedef unsigned short u16;
typedef short bf16x8 __attribute__((ext_vector_type(8)));
typedef float f32x4 __attribute__((ext_vector_type(4)));

__device__ __forceinline__ u16 f2bf(float f) {
    unsigned u = __builtin_bit_cast(unsigned, f);
    u += 0x7fffu + ((u >> 16) & 1u);   // RNE
    return (u16)(u >> 16);
}
__device__ __forceinline__ float bf2f(u16 h) {
    unsigned u = ((unsigned)h) << 16;
    return __builtin_bit_cast(float, u);
}

// ---------------- fused fp32 -> bf16 convert for all 5 tensors ---------------------
__global__ __launch_bounds__(256) void convert_all_k(const float* __restrict__ x,
                                                     const float* __restrict__ wq,
                                                     const float* __restrict__ wk,
                                                     const float* __restrict__ wv,
                                                     const float* __restrict__ wo_,
                                                     u16* __restrict__ xb,
                                                     u16* __restrict__ wqkv,
                                                     u16* __restrict__ wob) {
    int i = (blockIdx.x * 256 + threadIdx.x) * 4;
    const float* src;
    u16* dst;
    int off;
    if (i < 4194304) {
        src = x; dst = xb; off = i;
    } else if (i < 5242880) {
        src = wq; dst = wqkv; off = i - 4194304;
    } else if (i < 6291456) {
        src = wk; dst = wqkv + 1048576; off = i - 5242880;
    } else if (i < 7340032) {
        src = wv; dst = wqkv + 2097152; off = i - 6291456;
    } else {
        src = wo_; dst = wob; off = i - 7340032;
    }
    float4 v = *(const float4*)(src + off);
    uint2 o;
    o.x = (unsigned)f2bf(v.x) | ((unsigned)f2bf(v.y) << 16);
    o.y = (unsigned)f2bf(v.z) | ((unsigned)f2bf(v.w) << 16);
    *(uint2*)(dst + off) = o;
}

// ---------------- bf16 GEMM: C[m][n] = sum_k A[m][k]*Bw[n][k] ----------------------
// Double-buffered LDS with counted vmcnt (r7-proven pattern): prefetch K-step t+1
// while computing t; the 4 in-flight loads stay outstanding across the barrier.
// EPI==0: bf16 out, 3-segment bias (bq|bk|bv), fused RoPE on cols < 2048.
// EPI==1: fp32 out, bias0 only, no RoPE.
template <int EPI>
__global__ __launch_bounds__(256) void gemm_bt(const u16* __restrict__ A,
                                               const u16* __restrict__ Bw,
                                               const float* __restrict__ bias0,
                                               const float* __restrict__ bias1,
                                               const float* __restrict__ bias2,
                                               const int* __restrict__ days,
                                               u16* __restrict__ outB,
                                               float* __restrict__ outF,
                                               int M, int N, int K) {
    __shared__ __align__(16) u16 As[2][4096];
    __shared__ __align__(16) u16 Bs[2][4096];
    const int tid = threadIdx.x;
    const int lane = tid & 63;
    const int w = tid >> 6;
    const int wr = w >> 1, wc = w & 1;
    const int lr = lane & 15, lg = lane >> 4;
    const int nbn = N >> 7;
    const int m0 = (blockIdx.x / nbn) << 7;
    const int n0 = (blockIdx.x % nbn) << 7;

    f32x4 acc[4][4] = {};

    const u16* aptr[2];
    const u16* bptr[2];
    int ldsoff[2];
#pragma unroll
    for (int i = 0; i < 2; ++i) {
        int c = (w * 2 + i) * 64 + lane;
        int row = c >> 2, kc = (c & 3) << 3;
        aptr[i] = A + (size_t)(m0 + row) * K + kc;
        bptr[i] = Bw + (size_t)(n0 + row) * K + kc;
        ldsoff[i] = (w * 2 + i) * 512;
    }

#define GSTAGE(K0, BUF)                                                                \
    do {                                                                               \
        _Pragma("unroll") for (int i = 0; i < 2; ++i) {                                \
            __builtin_amdgcn_global_load_lds(                                          \
                (const __attribute__((address_space(1))) void*)(aptr[i] + (K0)),       \
                (__attribute__((address_space(3))) void*)(&As[BUF][ldsoff[i]]), 16, 0, \
                0);                                                                    \
            __builtin_amdgcn_global_load_lds(                                          \
                (const __attribute__((address_space(1))) void*)(bptr[i] + (K0)),       \
                (__attribute__((address_space(3))) void*)(&Bs[BUF][ldsoff[i]]), 16, 0, \
                0);                                                                    \
        }                                                                              \
    } while (0)

    const int nks = K >> 5;
    GSTAGE(0, 0);
    for (int ks = 0; ks < nks; ++ks) {
        const int cur = ks & 1;
        if (ks + 1 < nks) {
            GSTAGE((ks + 1) * 32, cur ^ 1);
            asm volatile("s_waitcnt vmcnt(4)" ::: "memory");
        } else {
            asm volatile("s_waitcnt vmcnt(0)" ::: "memory");
        }
        __builtin_amdgcn_s_barrier();
        bf16x8 af[4], bfr[4];
#pragma unroll
        for (int i = 0; i < 4; ++i)
            af[i] = *(const bf16x8*)(&As[cur][(wr * 64 + i * 16 + lr) * 32 + lg * 8]);
#pragma unroll
        for (int j = 0; j < 4; ++j)
            bfr[j] = *(const bf16x8*)(&Bs[cur][(wc * 64 + j * 16 + lr) * 32 + lg * 8]);
#pragma unroll
        for (int i = 0; i < 4; ++i)
#pragma unroll
            for (int j = 0; j < 4; ++j)
                acc[i][j] = __builtin_amdgcn_mfma_f32_16x16x32_bf16(af[i], bfr[j],
                                                                    acc[i][j], 0, 0, 0);
        __builtin_amdgcn_s_barrier();
    }
#undef GSTAGE

    auto bsel = [&](int ng) -> float {
        if (EPI != 0) return bias0[ng];
        return (ng < 1024) ? bias0[ng] : (ng < 2048) ? bias1[ng - 1024] : bias2[ng - 2048];
    };

    if (EPI == 0 && (n0 + wc * 64) < 2048) {
        // q/k region: wave's 64 cols = one full head; pairs (j, j+2) hold (x1, x2).
        const float C1 = -0.41524101186091903f;  // -log2(10000)/32
        const float inv0 = exp2f((float)lr * C1);
        const float inv1 = exp2f((float)(16 + lr) * C1);
#pragma unroll
        for (int i = 0; i < 4; ++i) {
            int mg = m0 + wr * 64 + i * 16 + lg * 4;
#pragma unroll
            for (int r = 0; r < 4; ++r) {
                int m = mg + r;
                int d = days[m];
                int ad = d < 0 ? -d : d;
                ad = ad > 2047 ? 2047 : ad;
                float pos = (float)ad;
#pragma unroll
                for (int j = 0; j < 2; ++j) {
                    int ng1 = n0 + wc * 64 + j * 16 + lr;
                    int ng2 = ng1 + 32;
                    float x1 = acc[i][j][r] + bsel(ng1);
                    float x2 = acc[i][j + 2][r] + bsel(ng2);
                    float ang = pos * (j ? inv1 : inv0);
                    float sn, cs;
                    __sincosf(ang, &sn, &cs);
                    outB[(size_t)m * N + ng1] = f2bf(x1 * cs - x2 * sn);
                    outB[(size_t)m * N + ng2] = f2bf(x2 * cs + x1 * sn);
                }
            }
        }
    } else {
#pragma unroll
        for (int i = 0; i < 4; ++i) {
            int mg = m0 + wr * 64 + i * 16 + lg * 4;
#pragma unroll
            for (int j = 0; j < 4; ++j) {
                int ng = n0 + wc * 64 + j * 16 + lr;
                float bias = bsel(ng);
#pragma unroll
                for (int r = 0; r < 4; ++r) {
                    float v = acc[i][j][r] + bias;
                    if (EPI == 0)
                        outB[(size_t)(mg + r) * N + ng] = f2bf(v);
                    else
                        outF[(size_t)(mg + r) * N + ng] = v;
                }
            }
        }
    }
}

// ---------------- V transpose: qkv v-region -> Vt[b,h,hd,s] ------------------------
__global__ __launch_bounds__(256) void v_transpose_k(const u16* __restrict__ qkv,
                                                     u16* __restrict__ vt) {
    __shared__ u16 tile[64][66];
    int st = blockIdx.x & 31;
    int bh = blockIdx.x >> 5;
    int b = bh >> 4, h = bh & 15;
    int s0 = st * 64;
    int t = threadIdx.x;
#pragma unroll
    for (int it = 0; it < 16; ++it) {
        int idx = it * 256 + t;
        int sr = idx >> 6, c = idx & 63;
        tile[sr][c] = qkv[(size_t)(b * 2048 + s0 + sr) * 3072 + 2048 + h * 64 + c];
    }
    __syncthreads();
#pragma unroll
    for (int it = 0; it < 16; ++it) {
        int idx = it * 256 + t;
        int hd = idx >> 6, sc = idx & 63;
        vt[((size_t)(bh * 64 + hd)) * 2048 + s0 + sc] = tile[sc][hd];
    }
}

// ---------------- flash attention (r7 structure + distant-tile fast path) ----------
__device__ __forceinline__ void attn_tile(const u16* __restrict__ Ks,
                                          const u16* __restrict__ Vs,
                                          u16* __restrict__ Pw,
                                          const int* __restrict__ dbk,
                                          float dkmax_c, bf16x8 pconst, float pcr,
                                          bf16x8 bq0, bf16x8 bq1, float dq_c, float c1,
                                          int qrel, bool domask,
                                          float& l_part, f32x4* acc, int lr, int lg) {
    if (!domask && __all(dkmax_c - dq_c < -20.0f)) {
        // distant tile: every p equals e^-12 (rel. err < 2^-14, below bf16 eps)
        l_part += 16.0f * pcr;
        __builtin_amdgcn_s_setprio(1);
#pragma unroll
        for (int pv = 0; pv < 2; ++pv) {
            int chunk = pv * 4 + lg;
#pragma unroll
            for (int c = 0; c < 4; ++c) {
                const int r3 = c * 16 + lr;
                bf16x8 bv = *(const bf16x8*)(Vs + r3 * 64 + ((chunk ^ (r3 & 7)) << 3));
                acc[c] = __builtin_amdgcn_mfma_f32_16x16x32_bf16(pconst, bv, acc[c], 0, 0, 0);
            }
        }
        __builtin_amdgcn_s_setprio(0);
        return;
    }
    f32x4 st_acc[4];
    __builtin_amdgcn_s_setprio(1);
#pragma unroll
    for (int st = 0; st < 4; ++st) {
        const int r2 = st * 16 + lr;
        const u16* kr = Ks + r2 * 64;
        bf16x8 ka0 = *(const bf16x8*)(kr + ((lg ^ (r2 & 7)) << 3));
        bf16x8 ka1 = *(const bf16x8*)(kr + (((4 + lg) ^ (r2 & 7)) << 3));
        f32x4 t = {};
        t = __builtin_amdgcn_mfma_f32_16x16x32_bf16(ka0, bq0, t, 0, 0, 0);
        t = __builtin_amdgcn_mfma_f32_16x16x32_bf16(ka1, bq1, t, 0, 0, 0);
        st_acc[st] = t;
    }
    __builtin_amdgcn_s_setprio(0);
    const float L2E = 1.4426950408889634f;
    const float POFF = 17.312340490667562f;  // 12*log2(e)
    float p[4][4];
#pragma unroll
    for (int st = 0; st < 4; ++st) {
        int4 dk4 = *(const int4*)(dbk + st * 16 + lg * 4);
#pragma unroll
        for (int r = 0; r < 4; ++r) {
            float dkf = (float)((&dk4.x)[r]);
            float dec = exp2f(__builtin_fmaf(dkf, c1, -dq_c));  // decay/8
            float v = st_acc[st][r] * dec;
            p[st][r] = exp2f(__builtin_fmaf(v, L2E, -POFF));
        }
    }
    if (domask) {
#pragma unroll
        for (int st = 0; st < 4; ++st)
#pragma unroll
            for (int r = 0; r < 4; ++r)
                p[st][r] = (st * 16 + lg * 4 + r <= qrel) ? p[st][r] : 0.f;
    }
#pragma unroll
    for (int st = 0; st < 4; ++st)
#pragma unroll
        for (int r = 0; r < 4; ++r) l_part += p[st][r];
#pragma unroll
    for (int st = 0; st < 4; ++st) {
        unsigned lo, hi;
        asm("v_cvt_pk_bf16_f32 %0, %1, %2" : "=v"(lo) : "v"(p[st][0]), "v"(p[st][1]));
        asm("v_cvt_pk_bf16_f32 %0, %1, %2" : "=v"(hi) : "v"(p[st][2]), "v"(p[st][3]));
        uint2 pk;
        pk.x = lo;
        pk.y = hi;
        int chunk = st * 2 + (lg >> 1);
        int idx = lr * 64 + ((chunk ^ (lr & 7)) << 3) + ((lg & 1) << 2);
        *(uint2*)&Pw[idx] = pk;
    }
    __builtin_amdgcn_s_setprio(1);
#pragma unroll
    for (int pv = 0; pv < 2; ++pv) {
        int chunk = pv * 4 + lg;
        bf16x8 pa = *(const bf16x8*)&Pw[lr * 64 + ((chunk ^ (lr & 7)) << 3)];
#pragma unroll
        for (int c = 0; c < 4; ++c) {
            const int r3 = c * 16 + lr;
            bf16x8 bv = *(const bf16x8*)(Vs + r3 * 64 + ((chunk ^ (r3 & 7)) << 3));
            acc[c] = __builtin_amdgcn_mfma_f32_16x16x32_bf16(pa, bv, acc[c], 0, 0, 0);
        }
    }
    __builtin_amdgcn_s_setprio(0);
}

__global__ __launch_bounds__(512, 4) void attn_k(const u16* __restrict__ qkv,
                                                 const u16* __restrict__ vt,
                                                 const int* __restrict__ days,
                                                 const float* __restrict__ decay_p,
                                                 u16* __restrict__ attn_out) {
    __shared__ __align__(16) u16 Ks[4][4096];   // 4 tile-slots: (pair-parity)*2 + group
    __shared__ __align__(16) u16 Vs[4][4096];
    __shared__ __align__(16) u16 Plds[8][1024];
    const int tid = threadIdx.x;
    const int lane = tid & 63;
    const int w = tid >> 6;      // 0..7
    const int qw = w & 3;        // q-row subtile within the 64-row q-tiles
    const int g = w >> 2;        // k-parity group
    const int lr = lane & 15, lg = lane >> 4;
    // bijective XCD swizzle (512 = 8 XCDs x 64): consecutive bh share an XCD's L2
    const int wg = (blockIdx.x & 7) * 64 + (blockIdx.x >> 3);
    const int j = wg & 15;
    const int bh = wg >> 4;
    const int b = bh >> 4, h = bh & 15;
    const int qtB = 31 - j;
    const int qbA = j * 64 + qw * 16;
    const int qbB = qtB * 64 + qw * 16;
    const float rate = decay_p[0];
    const float c1 = rate * 1.4426950408889634f;

    const u16* qmat = qkv + (size_t)b * 2048 * 3072 + h * 64;
    const u16* kmat = qmat + 1024;
    const u16* vtm = vt + (size_t)bh * 64 * 2048;
    const int* db = days + b * 2048;

    const int cp0 = (qw * 2 + 0) * 64 + lane;
    const int cp1 = (qw * 2 + 1) * 64 + lane;
    const int r0 = cp0 >> 3, c0 = cp0 & 7;
    const int r1 = cp1 >> 3, c1i = cp1 & 7;
    const u16* ksrc0 = kmat + (size_t)r0 * 3072 + ((c0 ^ (r0 & 7)) << 3);
    const u16* ksrc1 = kmat + (size_t)r1 * 3072 + ((c1i ^ (r1 & 7)) << 3);
    const u16* vsrc0 = vtm + (size_t)r0 * 2048 + ((c0 ^ (r0 & 7)) << 3);
    const u16* vsrc1 = vtm + (size_t)r1 * 2048 + ((c1i ^ (r1 & 7)) << 3);
    const int doff0 = (qw * 2 + 0) * 512;
    const int doff1 = (qw * 2 + 1) * 512;

#define STAGE(T, SLOT)                                                                 \
    do {                                                                               \
        __builtin_amdgcn_global_load_lds(                                              \
            (const __attribute__((address_space(1))) void*)(ksrc0 +                    \
                                                            (size_t)(T) * 64 * 3072), \
            (__attribute__((address_space(3))) void*)(&Ks[SLOT][doff0]), 16, 0, 0);    \
        __builtin_amdgcn_global_load_lds(                                              \
            (const __attribute__((address_space(1))) void*)(ksrc1 +                    \
                                                            (size_t)(T) * 64 * 3072), \
            (__attribute__((address_space(3))) void*)(&Ks[SLOT][doff1]), 16, 0, 0);    \
        __builtin_amdgcn_global_load_lds(                                              \
            (const __attribute__((address_space(1))) void*)(vsrc0 + (size_t)(T) * 64), \
            (__attribute__((address_space(3))) void*)(&Vs[SLOT][doff0]), 16, 0, 0);    \
        __builtin_amdgcn_global_load_lds(                                              \
            (const __attribute__((address_space(1))) void*)(vsrc1 + (size_t)(T) * 64), \
            (__attribute__((address_space(3))) void*)(&Vs[SLOT][doff1]), 16, 0, 0);    \
    } while (0)

    STAGE(g, g);  // pair 0: group g stages tile g into slot g

    bf16x8 bqA0, bqA1, bqB0, bqB1;
    {
        const u16* qpA = qmat + (size_t)(qbA + lr) * 3072 + lg * 8;
        bqA0 = *(const bf16x8*)qpA;
        bqA1 = *(const bf16x8*)(qpA + 32);
        const u16* qpB = qmat + (size_t)(qbB + lr) * 3072 + lg * 8;
        bqB0 = *(const bf16x8*)qpB;
        bqB1 = *(const bf16x8*)(qpB + 32);
    }
    // dq_c = (dq*rate + ln8)*log2e = dq*c1 + 3
    const float dq_cA = (float)db[qbA + lr] * c1 + 3.0f;
    const float dq_cB = (float)db[qbB + lr] * c1 + 3.0f;

    // constant P value for distant tiles: e^-12 (bf16-rounded, used for PV and l)
    const u16 pcu = f2bf(exp2f(-17.312340490667562f));
    const float pcr = bf2f(pcu);
    bf16x8 pconst;
#pragma unroll
    for (int i = 0; i < 8; ++i) pconst[i] = (short)pcu;

    float lA = 0.f, lB = 0.f;
    f32x4 accA[4] = {};
    f32x4 accB[4] = {};

    const int nkt = (33 - j) >> 1;  // ceil((32-j)/2) tile-pairs
    for (int it = 0; it < nkt; ++it) {
        const int kt = 2 * it + g;
        const int cur = ((it & 1) << 1) + g;
        if (it + 1 < nkt) {
            STAGE(2 * (it + 1) + g, (((it + 1) & 1) << 1) + g);
            asm volatile("s_waitcnt vmcnt(4)" ::: "memory");
        } else {
            asm volatile("s_waitcnt vmcnt(0)" ::: "memory");
        }
        __builtin_amdgcn_s_barrier();
        const int* dbk = db + kt * 64;
        const float dkmax_c = (float)dbk[63] * c1;  // sorted -> tile max
        if (kt <= qtB)
            attn_tile(Ks[cur], Vs[cur], Plds[w], dbk, dkmax_c, pconst, pcr,
                      bqB0, bqB1, dq_cB, c1, qw * 16 + lr, kt == qtB, lB, accB, lr, lg);
        if (kt <= j)
            attn_tile(Ks[cur], Vs[cur], Plds[w], dbk, dkmax_c, pconst, pcr,
                      bqA0, bqA1, dq_cA, c1, qw * 16 + lr, kt == j, lA, accA, lr, lg);
        __builtin_amdgcn_s_barrier();
    }
#undef STAGE

    // merge group partials through LDS, then group 0 writes output
    float* xch = (float*)&Plds[0][0];  // 4096 floats = 4 qw-regions x 64 lanes x 16
    float* lx = (float*)&Ks[0][0];     // l exchange
#pragma unroll
    for (int t = 0; t < 2; ++t) {
        float lp = t ? lA : lB;
        f32x4* acc = t ? accA : accB;
        const int qt = t ? j : qtB;
        __syncthreads();
        if (g == 1) {
            float* dst = xch + qw * 1024 + lane * 16;
#pragma unroll
            for (int c = 0; c < 4; ++c) *(f32x4*)(dst + c * 4) = acc[c];
            lx[qw * 64 + lane] = lp;
        }
        __syncthreads();
        if (g == 0) {
            const float* src = xch + qw * 1024 + lane * 16;
#pragma unroll
            for (int c = 0; c < 4; ++c) acc[c] += *(const f32x4*)(src + c * 4);
            lp += lx[qw * 64 + lane];
            float l_full = lp + __shfl_xor(lp, 16);
            l_full += __shfl_xor(l_full, 32);
            float inv_[4];
#pragma unroll
            for (int r = 0; r < 4; ++r) inv_[r] = 1.0f / __shfl(l_full, lg * 4 + r);
#pragma unroll
            for (int c = 0; c < 4; ++c)
#pragma unroll
                for (int r = 0; r < 4; ++r) {
                    const int qg = qt * 64 + qw * 16 + lg * 4 + r;
                    attn_out[(size_t)(b * 2048 + qg) * 1024 + h * 64 + c * 16 + lr] =
                        f2bf(acc[c][r] * inv_[r]);
                }
        }
    }
}

// ---------------- launch -----------------------------------------------------------
extern "C" void kernel_launch(void* const* d_in, const int* in_sizes, int n_in,
                              void* d_out, int out_size, void* d_ws, size_t ws_size,
                              hipStream_t stream) {
    const float* x = (const float*)d_in[0];
    const float* Wq = (const float*)d_in[1];
    const float* bq = (const float*)d_in[2];
    const float* Wk = (const float*)d_in[3];
    const float* bk = (const float*)d_in[4];
    const float* Wv = (const float*)d_in[5];
    const float* bv = (const float*)d_in[6];
    const float* Wo = (const float*)d_in[7];
    const float* bo = (const float*)d_in[8];
    const float* decay = (const float*)d_in[9];
    const int* days = (const int*)d_in[11];
    float* out = (float*)d_out;

    char* ws = (char*)d_ws;
    u16* xb = (u16*)(ws);                   //  8 MB: x bf16 [4096][1024]
    u16* wqkv = (u16*)(ws + 8388608);       //  6 MB: [Wq;Wk;Wv] bf16 [3072][1024]
    u16* wo = (u16*)(ws + 14680064);        //  2 MB: Wo bf16 [1024][1024]
    u16* qkvb = (u16*)(ws + 16777216);      // 24 MB: qkv bf16 [4096][3072]
    u16* vtb = (u16*)(ws + 41943040);       //  8 MB: Vt bf16 [32][64][2048]
    u16* attb = (u16*)(ws + 50331648);      //  8 MB: attn out bf16 [4096][1024]

    convert_all_k<<<8192, 256, 0, stream>>>(x, Wq, Wk, Wv, Wo, xb, wqkv, wo);

    gemm_bt<0><<<768, 256, 0, stream>>>(xb, wqkv, bq, bk, bv, days, qkvb, nullptr,
                                        4096, 3072, 1024);
    v_transpose_k<<<1024, 256, 0, stream>>>(qkvb, vtb);
    attn_k<<<512, 512, 0, stream>>>(qkvb, vtb, days, decay, attb);
    gemm_bt<1><<<256, 256, 0, stream>>>(attb, wo, bo, nullptr, nullptr, days, nullptr,
                                        out, 4096, 1024, 1024);
}

// Round 13
// 105.279 us; speedup vs baseline: 1.6314x; 1.0590x over previous
//
#include <hip/hip_runtime.h>
#include <hip/hip_bf16.h>

// B=2, S=2048, D=1024, H=16, HD=64. fp32 in, fp32 out, bf16-tolerance threshold.
// Pipeline: convert->bf16 | QKV GEMM (fused bias+RoPE, dbuf) | V-transpose |
//           V-prefix-sum | flash attn v9 (per-q-tile block, far region via VPS,
//           exact tiles only in [t0,qt]) | out GEMM.

typedef unsigned short u16;
typedef short bf16x8 __attribute__((ext_vector_type(8)));
typedef float f32x4 __attribute__((ext_vector_type(4)));

__device__ __forceinline__ u16 f2bf(float f) {
    unsigned u = __builtin_bit_cast(unsigned, f);
    u += 0x7fffu + ((u >> 16) & 1u);   // RNE
    return (u16)(u >> 16);
}
__device__ __forceinline__ float bf2f(u16 h) {
    unsigned u = ((unsigned)h) << 16;
    return __builtin_bit_cast(float, u);
}

// ---------------- fused fp32 -> bf16 convert for all 5 tensors ---------------------
__global__ __launch_bounds__(256) void convert_all_k(const float* __restrict__ x,
                                                     const float* __restrict__ wq,
                                                     const float* __restrict__ wk,
                                                     const float* __restrict__ wv,
                                                     const float* __restrict__ wo_,
                                                     u16* __restrict__ xb,
                                                     u16* __restrict__ wqkv,
                                                     u16* __restrict__ wob) {
    int i = (blockIdx.x * 256 + threadIdx.x) * 4;
    const float* src;
    u16* dst;
    int off;
    if (i < 4194304) {
        src = x; dst = xb; off = i;
    } else if (i < 5242880) {
        src = wq; dst = wqkv; off = i - 4194304;
    } else if (i < 6291456) {
        src = wk; dst = wqkv + 1048576; off = i - 5242880;
    } else if (i < 7340032) {
        src = wv; dst = wqkv + 2097152; off = i - 6291456;
    } else {
        src = wo_; dst = wob; off = i - 7340032;
    }
    float4 v = *(const float4*)(src + off);
    uint2 o;
    o.x = (unsigned)f2bf(v.x) | ((unsigned)f2bf(v.y) << 16);
    o.y = (unsigned)f2bf(v.z) | ((unsigned)f2bf(v.w) << 16);
    *(uint2*)(dst + off) = o;
}

// ---------------- bf16 GEMM: C[m][n] = sum_k A[m][k]*Bw[n][k] ----------------------
// Double-buffered LDS with counted vmcnt. EPI==0: bf16 out, 3-seg bias, fused RoPE.
// EPI==1: fp32 out, bias0 only.
template <int EPI>
__global__ __launch_bounds__(256) void gemm_bt(const u16* __restrict__ A,
                                               const u16* __restrict__ Bw,
                                               const float* __restrict__ bias0,
                                               const float* __restrict__ bias1,
                                               const float* __restrict__ bias2,
                                               const int* __restrict__ days,
                                               u16* __restrict__ outB,
                                               float* __restrict__ outF,
                                               int M, int N, int K) {
    __shared__ __align__(16) u16 As[2][4096];
    __shared__ __align__(16) u16 Bs[2][4096];
    const int tid = threadIdx.x;
    const int lane = tid & 63;
    const int w = tid >> 6;
    const int wr = w >> 1, wc = w & 1;
    const int lr = lane & 15, lg = lane >> 4;
    const int nbn = N >> 7;
    const int m0 = (blockIdx.x / nbn) << 7;
    const int n0 = (blockIdx.x % nbn) << 7;

    f32x4 acc[4][4] = {};

    const u16* aptr[2];
    const u16* bptr[2];
    int ldsoff[2];
#pragma unroll
    for (int i = 0; i < 2; ++i) {
        int c = (w * 2 + i) * 64 + lane;
        int row = c >> 2, kc = (c & 3) << 3;
        aptr[i] = A + (size_t)(m0 + row) * K + kc;
        bptr[i] = Bw + (size_t)(n0 + row) * K + kc;
        ldsoff[i] = (w * 2 + i) * 512;
    }

#define GSTAGE(K0, BUF)                                                                \
    do {                                                                               \
        _Pragma("unroll") for (int i = 0; i < 2; ++i) {                                \
            __builtin_amdgcn_global_load_lds(                                          \
                (const __attribute__((address_space(1))) void*)(aptr[i] + (K0)),       \
                (__attribute__((address_space(3))) void*)(&As[BUF][ldsoff[i]]), 16, 0, \
                0);                                                                    \
            __builtin_amdgcn_global_load_lds(                                          \
                (const __attribute__((address_space(1))) void*)(bptr[i] + (K0)),       \
                (__attribute__((address_space(3))) void*)(&Bs[BUF][ldsoff[i]]), 16, 0, \
                0);                                                                    \
        }                                                                              \
    } while (0)

    const int nks = K >> 5;
    GSTAGE(0, 0);
    for (int ks = 0; ks < nks; ++ks) {
        const int cur = ks & 1;
        if (ks + 1 < nks) {
            GSTAGE((ks + 1) * 32, cur ^ 1);
            asm volatile("s_waitcnt vmcnt(4)" ::: "memory");
        } else {
            asm volatile("s_waitcnt vmcnt(0)" ::: "memory");
        }
        __builtin_amdgcn_s_barrier();
        bf16x8 af[4], bfr[4];
#pragma unroll
        for (int i = 0; i < 4; ++i)
            af[i] = *(const bf16x8*)(&As[cur][(wr * 64 + i * 16 + lr) * 32 + lg * 8]);
#pragma unroll
        for (int j = 0; j < 4; ++j)
            bfr[j] = *(const bf16x8*)(&Bs[cur][(wc * 64 + j * 16 + lr) * 32 + lg * 8]);
#pragma unroll
        for (int i = 0; i < 4; ++i)
#pragma unroll
            for (int j = 0; j < 4; ++j)
                acc[i][j] = __builtin_amdgcn_mfma_f32_16x16x32_bf16(af[i], bfr[j],
                                                                    acc[i][j], 0, 0, 0);
        __builtin_amdgcn_s_barrier();
    }
#undef GSTAGE

    auto bsel = [&](int ng) -> float {
        if (EPI != 0) return bias0[ng];
        return (ng < 1024) ? bias0[ng] : (ng < 2048) ? bias1[ng - 1024] : bias2[ng - 2048];
    };

    if (EPI == 0 && (n0 + wc * 64) < 2048) {
        const float C1 = -0.41524101186091903f;  // -log2(10000)/32
        const float inv0 = exp2f((float)lr * C1);
        const float inv1 = exp2f((float)(16 + lr) * C1);
#pragma unroll
        for (int i = 0; i < 4; ++i) {
            int mg = m0 + wr * 64 + i * 16 + lg * 4;
#pragma unroll
            for (int r = 0; r < 4; ++r) {
                int m = mg + r;
                int d = days[m];
                int ad = d < 0 ? -d : d;
                ad = ad > 2047 ? 2047 : ad;
                float pos = (float)ad;
#pragma unroll
                for (int j = 0; j < 2; ++j) {
                    int ng1 = n0 + wc * 64 + j * 16 + lr;
                    int ng2 = ng1 + 32;
                    float x1 = acc[i][j][r] + bsel(ng1);
                    float x2 = acc[i][j + 2][r] + bsel(ng2);
                    float ang = pos * (j ? inv1 : inv0);
                    float sn, cs;
                    __sincosf(ang, &sn, &cs);
                    outB[(size_t)m * N + ng1] = f2bf(x1 * cs - x2 * sn);
                    outB[(size_t)m * N + ng2] = f2bf(x2 * cs + x1 * sn);
                }
            }
        }
    } else {
#pragma unroll
        for (int i = 0; i < 4; ++i) {
            int mg = m0 + wr * 64 + i * 16 + lg * 4;
#pragma unroll
            for (int j = 0; j < 4; ++j) {
                int ng = n0 + wc * 64 + j * 16 + lr;
                float bias = bsel(ng);
#pragma unroll
                for (int r = 0; r < 4; ++r) {
                    float v = acc[i][j][r] + bias;
                    if (EPI == 0)
                        outB[(size_t)(mg + r) * N + ng] = f2bf(v);
                    else
                        outF[(size_t)(mg + r) * N + ng] = v;
                }
            }
        }
    }
}

// ---------------- V transpose: qkv v-region -> Vt[b,h,hd,s] ------------------------
__global__ __launch_bounds__(256) void v_transpose_k(const u16* __restrict__ qkv,
                                                     u16* __restrict__ vt) {
    __shared__ u16 tile[64][66];
    int st = blockIdx.x & 31;
    int bh = blockIdx.x >> 5;
    int b = bh >> 4, h = bh & 15;
    int s0 = st * 64;
    int t = threadIdx.x;
#pragma unroll
    for (int it = 0; it < 16; ++it) {
        int idx = it * 256 + t;
        int sr = idx >> 6, c = idx & 63;
        tile[sr][c] = qkv[(size_t)(b * 2048 + s0 + sr) * 3072 + 2048 + h * 64 + c];
    }
    __syncthreads();
#pragma unroll
    for (int it = 0; it < 16; ++it) {
        int idx = it * 256 + t;
        int hd = idx >> 6, sc = idx & 63;
        vt[((size_t)(bh * 64 + hd)) * 2048 + s0 + sc] = tile[sc][hd];
    }
}

// ---------------- V prefix sums over k-tiles: VPS[bh][t][d], t in [0,32] -----------
// VPS[bh][t][d] = sum_{s < t*64} Vt[bh][d][s]   (fp32, exclusive prefix)
__global__ __launch_bounds__(256) void vps_k(const u16* __restrict__ vt,
                                             float* __restrict__ vps) {
    __shared__ float ts[32][32];
    const int bh = blockIdx.x >> 1;
    const int d0 = (blockIdx.x & 1) * 32;
    const int dl = threadIdx.x >> 3;   // 0..31 local d
    const int seg = threadIdx.x & 7;   // 4 tiles each
    const u16* vrow = vt + ((size_t)bh * 64 + d0 + dl) * 2048 + seg * 256;
#pragma unroll
    for (int tt = 0; tt < 4; ++tt) {
        float s = 0.f;
#pragma unroll
        for (int i = 0; i < 8; ++i) {
            bf16x8 v = *(const bf16x8*)(vrow + tt * 64 + i * 8);
#pragma unroll
            for (int e = 0; e < 8; ++e) s += bf2f((u16)v[e]);
        }
        ts[dl][seg * 4 + tt] = s;
    }
    __syncthreads();
    if (threadIdx.x < 32) {
        int d = threadIdx.x;
        float acc = 0.f;
        for (int t = 0; t <= 32; ++t) {
            vps[((size_t)bh * 33 + t) * 64 + d0 + d] = acc;
            if (t < 32) acc += ts[d][t];
        }
    }
}

// ---------------- flash attention v9 -----------------------------------------------
// One block per (bh, q-tile): 4 waves x 16 q-rows. Far region [0, t0) folded into a
// single VPS lookup (acc = pcr*VPS[t0], l += t0*16*pcr); k-loop runs only [t0, qt]
// (~3-6 tiles). t0 = block-uniform prefix boundary from row qt*64 (min dq). Per-wave
// in-loop fast path (r11) retained for tiles in [t0, per-wave tfar). Tile body,
// staging, epilogue identical to the proven r3/r11 code.

__device__ __forceinline__ void attn_tile(const u16* __restrict__ Ks,
                                          const u16* __restrict__ Vs,
                                          u16* __restrict__ Pw,
                                          const int* __restrict__ dbk,
                                          float dkmax_c, bf16x8 pconst, float pcr,
                                          bf16x8 bq0, bf16x8 bq1, float dq_c, float c1,
                                          int qrel, bool domask,
                                          float& l_part, f32x4* acc, int lr, int lg) {
    if (!domask && __all(dkmax_c - dq_c < -20.0f)) {
        l_part += 16.0f * pcr;
        __builtin_amdgcn_s_setprio(1);
#pragma unroll
        for (int pv = 0; pv < 2; ++pv) {
            int chunk = pv * 4 + lg;
#pragma unroll
            for (int c = 0; c < 4; ++c) {
                const int r3 = c * 16 + lr;
                bf16x8 bv = *(const bf16x8*)(Vs + r3 * 64 + ((chunk ^ (r3 & 7)) << 3));
                acc[c] = __builtin_amdgcn_mfma_f32_16x16x32_bf16(pconst, bv, acc[c], 0, 0, 0);
            }
        }
        __builtin_amdgcn_s_setprio(0);
        return;
    }
    f32x4 st_acc[4];
    __builtin_amdgcn_s_setprio(1);
#pragma unroll
    for (int st = 0; st < 4; ++st) {
        const int r2 = st * 16 + lr;
        const u16* kr = Ks + r2 * 64;
        bf16x8 ka0 = *(const bf16x8*)(kr + ((lg ^ (r2 & 7)) << 3));
        bf16x8 ka1 = *(const bf16x8*)(kr + (((4 + lg) ^ (r2 & 7)) << 3));
        f32x4 t = {};
        t = __builtin_amdgcn_mfma_f32_16x16x32_bf16(ka0, bq0, t, 0, 0, 0);
        t = __builtin_amdgcn_mfma_f32_16x16x32_bf16(ka1, bq1, t, 0, 0, 0);
        st_acc[st] = t;
    }
    __builtin_amdgcn_s_setprio(0);
    const float L2E = 1.4426950408889634f;
    const float POFF = 17.312340490667562f;  // 12*log2(e)
    float p[4][4];
#pragma unroll
    for (int st = 0; st < 4; ++st) {
        int4 dk4 = *(const int4*)(dbk + st * 16 + lg * 4);
#pragma unroll
        for (int r = 0; r < 4; ++r) {
            float dkf = (float)((&dk4.x)[r]);
            float dec = exp2f(__builtin_fmaf(dkf, c1, -dq_c));  // decay/8
            float v = st_acc[st][r] * dec;
            p[st][r] = exp2f(__builtin_fmaf(v, L2E, -POFF));
        }
    }
    if (domask) {
#pragma unroll
        for (int st = 0; st < 4; ++st)
#pragma unroll
            for (int r = 0; r < 4; ++r)
                p[st][r] = (st * 16 + lg * 4 + r <= qrel) ? p[st][r] : 0.f;
    }
#pragma unroll
    for (int st = 0; st < 4; ++st)
#pragma unroll
        for (int r = 0; r < 4; ++r) l_part += p[st][r];
#pragma unroll
    for (int st = 0; st < 4; ++st) {
        unsigned lo, hi;
        asm("v_cvt_pk_bf16_f32 %0, %1, %2" : "=v"(lo) : "v"(p[st][0]), "v"(p[st][1]));
        asm("v_cvt_pk_bf16_f32 %0, %1, %2" : "=v"(hi) : "v"(p[st][2]), "v"(p[st][3]));
        uint2 pk;
        pk.x = lo;
        pk.y = hi;
        int chunk = st * 2 + (lg >> 1);
        int idx = lr * 64 + ((chunk ^ (lr & 7)) << 3) + ((lg & 1) << 2);
        *(uint2*)&Pw[idx] = pk;
    }
    __builtin_amdgcn_s_setprio(1);
#pragma unroll
    for (int pv = 0; pv < 2; ++pv) {
        int chunk = pv * 4 + lg;
        bf16x8 pa = *(const bf16x8*)&Pw[lr * 64 + ((chunk ^ (lr & 7)) << 3)];
#pragma unroll
        for (int c = 0; c < 4; ++c) {
            const int r3 = c * 16 + lr;
            bf16x8 bv = *(const bf16x8*)(Vs + r3 * 64 + ((chunk ^ (r3 & 7)) << 3));
            acc[c] = __builtin_amdgcn_mfma_f32_16x16x32_bf16(pa, bv, acc[c], 0, 0, 0);
        }
    }
    __builtin_amdgcn_s_setprio(0);
}

__global__ __launch_bounds__(256, 4) void attn_k(const u16* __restrict__ qkv,
                                                 const u16* __restrict__ vt,
                                                 const int* __restrict__ days,
                                                 const float* __restrict__ decay_p,
                                                 const float* __restrict__ vps,
                                                 u16* __restrict__ attn_out) {
    __shared__ __align__(16) u16 Ks[2][4096];
    __shared__ __align__(16) u16 Vs[2][4096];
    __shared__ __align__(16) u16 Plds[4][1024];
    const int tid = threadIdx.x;
    const int lane = tid & 63;
    const int w = tid >> 6;
    const int lr = lane & 15, lg = lane >> 4;
    // bijective XCD swizzle (1024 = 8 x 128): all q-tiles of a bh share an XCD's L2
    const int wg = (blockIdx.x & 7) * 128 + (blockIdx.x >> 3);
    const int qt = wg & 31;
    const int bh = wg >> 5;
    const int b = bh >> 4, h = bh & 15;
    const int qb = qt * 64 + w * 16;
    const float rate = decay_p[0];
    const float c1 = rate * 1.4426950408889634f;

    const u16* qmat = qkv + (size_t)b * 2048 * 3072 + h * 64;
    const u16* kmat = qmat + 1024;
    const u16* vtm = vt + (size_t)bh * 64 * 2048;
    const int* db = days + b * 2048;

    // staging: 4 waves cover the 512 16B-chunks of one 64x64 tile.
    const int cp0 = (w * 2 + 0) * 64 + lane;
    const int cp1 = (w * 2 + 1) * 64 + lane;
    const int r0 = cp0 >> 3, c0 = cp0 & 7;
    const int r1 = cp1 >> 3, c1i = cp1 & 7;
    const u16* ksrc0 = kmat + (size_t)r0 * 3072 + ((c0 ^ (r0 & 7)) << 3);
    const u16* ksrc1 = kmat + (size_t)r1 * 3072 + ((c1i ^ (r1 & 7)) << 3);
    const u16* vsrc0 = vtm + (size_t)r0 * 2048 + ((c0 ^ (r0 & 7)) << 3);
    const u16* vsrc1 = vtm + (size_t)r1 * 2048 + ((c1i ^ (r1 & 7)) << 3);
    const int doff0 = (w * 2 + 0) * 512;
    const int doff1 = (w * 2 + 1) * 512;

#define STAGE(T, SLOT)                                                                 \
    do {                                                                               \
        __builtin_amdgcn_global_load_lds(                                              \
            (const __attribute__((address_space(1))) void*)(ksrc0 +                    \
                                                            (size_t)(T) * 64 * 3072), \
            (__attribute__((address_space(3))) void*)(&Ks[SLOT][doff0]), 16, 0, 0);    \
        __builtin_amdgcn_global_load_lds(                                              \
            (const __attribute__((address_space(1))) void*)(ksrc1 +                    \
                                                            (size_t)(T) * 64 * 3072), \
            (__attribute__((address_space(3))) void*)(&Ks[SLOT][doff1]), 16, 0, 0);    \
        __builtin_amdgcn_global_load_lds(                                              \
            (const __attribute__((address_space(1))) void*)(vsrc0 + (size_t)(T) * 64), \
            (__attribute__((address_space(3))) void*)(&Vs[SLOT][doff0]), 16, 0, 0);    \
        __builtin_amdgcn_global_load_lds(                                              \
            (const __attribute__((address_space(1))) void*)(vsrc1 + (size_t)(T) * 64), \
            (__attribute__((address_space(3))) void*)(&Vs[SLOT][doff1]), 16, 0, 0);    \
    } while (0)

    // block-uniform far boundary t0: first kt whose tile-max day fails the far test
    // against the block's minimum dq (row qt*64; days sorted => prefix property).
    const float dq00_c = (float)db[qt * 64] * c1 + 3.0f;
    int t0;
    {
        const int l32 = lane & 31;
        float dm = (float)db[l32 * 64 + 63] * c1;
        bool cnd = (lane < qt) && (dm < dq00_c - 20.0f);
        unsigned long long m = __ballot(cnd);
        t0 = (int)__builtin_ctzll(~m);
    }

    STAGE(t0, 0);

    bf16x8 bq0, bq1;
    {
        const u16* qp = qmat + (size_t)(qb + lr) * 3072 + lg * 8;
        bq0 = *(const bf16x8*)qp;
        bq1 = *(const bf16x8*)(qp + 32);
    }
    const float dq_c = (float)db[qb + lr] * c1 + 3.0f;

    // constant P value for far tiles: e^-12 (bf16-rounded)
    const u16 pcu = f2bf(exp2f(-17.312340490667562f));
    const float pcr = bf2f(pcu);
    bf16x8 pconst;
#pragma unroll
    for (int i = 0; i < 8; ++i) pconst[i] = (short)pcu;

    // init from V prefix sums: O_far = pcr * VPS[t0][:], l_far = t0*16*pcr per lane
    float lp = (float)t0 * 16.0f * pcr;
    f32x4 acc[4];
#pragma unroll
    for (int c = 0; c < 4; ++c) {
        float vv = pcr * vps[((size_t)bh * 33 + t0) * 64 + c * 16 + lr];
        acc[c] = (f32x4){vv, vv, vv, vv};
    }

    for (int kt = t0; kt <= qt; ++kt) {
        const int cur = (kt - t0) & 1;
        if (kt < qt) {
            STAGE(kt + 1, cur ^ 1);
            asm volatile("s_waitcnt vmcnt(4)" ::: "memory");
        } else {
            asm volatile("s_waitcnt vmcnt(0)" ::: "memory");
        }
        __builtin_amdgcn_s_barrier();
        const int* dbk = db + kt * 64;
        const float dkmax_c = (float)dbk[63] * c1;
        attn_tile(Ks[cur], Vs[cur], Plds[w], dbk, dkmax_c, pconst, pcr,
                  bq0, bq1, dq_c, c1, w * 16 + lr, kt == qt, lp, acc, lr, lg);
        __builtin_amdgcn_s_barrier();
    }
#undef STAGE

    float l_full = lp + __shfl_xor(lp, 16);
    l_full += __shfl_xor(l_full, 32);
    float inv_[4];
#pragma unroll
    for (int r = 0; r < 4; ++r) inv_[r] = 1.0f / __shfl(l_full, lg * 4 + r);
#pragma unroll
    for (int c = 0; c < 4; ++c)
#pragma unroll
        for (int r = 0; r < 4; ++r) {
            const int qg = qb + lg * 4 + r;
            attn_out[(size_t)(b * 2048 + qg) * 1024 + h * 64 + c * 16 + lr] =
                f2bf(acc[c][r] * inv_[r]);
        }
}

// ---------------- launch -----------------------------------------------------------
extern "C" void kernel_launch(void* const* d_in, const int* in_sizes, int n_in,
                              void* d_out, int out_size, void* d_ws, size_t ws_size,
                              hipStream_t stream) {
    const float* x = (const float*)d_in[0];
    const float* Wq = (const float*)d_in[1];
    const float* bq = (const float*)d_in[2];
    const float* Wk = (const float*)d_in[3];
    const float* bk = (const float*)d_in[4];
    const float* Wv = (const float*)d_in[5];
    const float* bv = (const float*)d_in[6];
    const float* Wo = (const float*)d_in[7];
    const float* bo = (const float*)d_in[8];
    const float* decay = (const float*)d_in[9];
    const int* days = (const int*)d_in[11];
    float* out = (float*)d_out;

    char* ws = (char*)d_ws;
    u16* xb = (u16*)(ws);                   //  8 MB: x bf16 [4096][1024]
    u16* wqkv = (u16*)(ws + 8388608);       //  6 MB: [Wq;Wk;Wv] bf16 [3072][1024]
    u16* wo = (u16*)(ws + 14680064);        //  2 MB: Wo bf16 [1024][1024]
    u16* qkvb = (u16*)(ws + 16777216);      // 24 MB: qkv bf16 [4096][3072]
    u16* vtb = (u16*)(ws + 41943040);       //  8 MB: Vt bf16 [32][64][2048]
    u16* attb = (u16*)(ws + 50331648);      //  8 MB: attn out bf16 [4096][1024]
    float* vpsb = (float*)(ws + 58720256);  // 270 KB: V prefix sums [32][33][64] f32

    convert_all_k<<<8192, 256, 0, stream>>>(x, Wq, Wk, Wv, Wo, xb, wqkv, wo);

    gemm_bt<0><<<768, 256, 0, stream>>>(xb, wqkv, bq, bk, bv, days, qkvb, nullptr,
                                        4096, 3072, 1024);
    v_transpose_k<<<1024, 256, 0, stream>>>(qkvb, vtb);
    vps_k<<<64, 256, 0, stream>>>(vtb, vpsb);
    attn_k<<<1024, 256, 0, stream>>>(qkvb, vtb, days, decay, vpsb, attb);
    gemm_bt<1><<<256, 256, 0, stream>>>(attb, wo, bo, nullptr, nullptr, days, nullptr,
                                        out, 4096, 1024, 1024);
}

// Round 14
// 104.843 us; speedup vs baseline: 1.6382x; 1.0042x over previous
//
#include <hip/hip_runtime.h>
#include <hip/hip_bf16.h>

// B=2, S=2048, D=1024, H=16, HD=64. fp32 in, fp32 out, bf16-tolerance threshold.
// Pipeline: convert->bf16 | QKV GEMM (fused bias+RoPE, 3-slot dbuf depth-2 prefetch) |
//           V-transpose | V-prefix-sum | flash attn v9 (far region via VPS) | out GEMM.

typedef unsigned short u16;
typedef short bf16x8 __attribute__((ext_vector_type(8)));
typedef float f32x4 __attribute__((ext_vector_type(4)));

__device__ __forceinline__ u16 f2bf(float f) {
    unsigned u = __builtin_bit_cast(unsigned, f);
    u += 0x7fffu + ((u >> 16) & 1u);   // RNE
    return (u16)(u >> 16);
}
__device__ __forceinline__ float bf2f(u16 h) {
    unsigned u = ((unsigned)h) << 16;
    return __builtin_bit_cast(float, u);
}

// ---------------- fused fp32 -> bf16 convert for all 5 tensors ---------------------
__global__ __launch_bounds__(256) void convert_all_k(const float* __restrict__ x,
                                                     const float* __restrict__ wq,
                                                     const float* __restrict__ wk,
                                                     const float* __restrict__ wv,
                                                     const float* __restrict__ wo_,
                                                     u16* __restrict__ xb,
                                                     u16* __restrict__ wqkv,
                                                     u16* __restrict__ wob) {
    int i = (blockIdx.x * 256 + threadIdx.x) * 4;
    const float* src;
    u16* dst;
    int off;
    if (i < 4194304) {
        src = x; dst = xb; off = i;
    } else if (i < 5242880) {
        src = wq; dst = wqkv; off = i - 4194304;
    } else if (i < 6291456) {
        src = wk; dst = wqkv + 1048576; off = i - 5242880;
    } else if (i < 7340032) {
        src = wv; dst = wqkv + 2097152; off = i - 6291456;
    } else {
        src = wo_; dst = wob; off = i - 7340032;
    }
    float4 v = *(const float4*)(src + off);
    uint2 o;
    o.x = (unsigned)f2bf(v.x) | ((unsigned)f2bf(v.y) << 16);
    o.y = (unsigned)f2bf(v.z) | ((unsigned)f2bf(v.w) << 16);
    *(uint2*)(dst + off) = o;
}

// ---------------- bf16 GEMM: C[m][n] = sum_k A[m][k]*Bw[n][k] ----------------------
// 3-slot LDS ring, prefetch depth 2, counted vmcnt(8): step t issues t+2's loads;
// FIFO order => <=8 outstanding means step t's 4 loads have landed.
// EPI==0: bf16 out, 3-seg bias, fused RoPE on cols < 2048. EPI==1: fp32 out, bias0.
template <int EPI>
__global__ __launch_bounds__(256) void gemm_bt(const u16* __restrict__ A,
                                               const u16* __restrict__ Bw,
                                               const float* __restrict__ bias0,
                                               const float* __restrict__ bias1,
                                               const float* __restrict__ bias2,
                                               const int* __restrict__ days,
                                               u16* __restrict__ outB,
                                               float* __restrict__ outF,
                                               int M, int N, int K) {
    __shared__ __align__(16) u16 As[3][4096];
    __shared__ __align__(16) u16 Bs[3][4096];
    const int tid = threadIdx.x;
    const int lane = tid & 63;
    const int w = tid >> 6;
    const int wr = w >> 1, wc = w & 1;
    const int lr = lane & 15, lg = lane >> 4;
    const int nbn = N >> 7;
    const int m0 = (blockIdx.x / nbn) << 7;
    const int n0 = (blockIdx.x % nbn) << 7;

    f32x4 acc[4][4] = {};

    const u16* aptr[2];
    const u16* bptr[2];
    int ldsoff[2];
#pragma unroll
    for (int i = 0; i < 2; ++i) {
        int c = (w * 2 + i) * 64 + lane;
        int row = c >> 2, kc = (c & 3) << 3;
        aptr[i] = A + (size_t)(m0 + row) * K + kc;
        bptr[i] = Bw + (size_t)(n0 + row) * K + kc;
        ldsoff[i] = (w * 2 + i) * 512;
    }

#define GSTAGE(K0, BUF)                                                                \
    do {                                                                               \
        _Pragma("unroll") for (int i = 0; i < 2; ++i) {                                \
            __builtin_amdgcn_global_load_lds(                                          \
                (const __attribute__((address_space(1))) void*)(aptr[i] + (K0)),       \
                (__attribute__((address_space(3))) void*)(&As[BUF][ldsoff[i]]), 16, 0, \
                0);                                                                    \
            __builtin_amdgcn_global_load_lds(                                          \
                (const __attribute__((address_space(1))) void*)(bptr[i] + (K0)),       \
                (__attribute__((address_space(3))) void*)(&Bs[BUF][ldsoff[i]]), 16, 0, \
                0);                                                                    \
        }                                                                              \
    } while (0)

    const int nks = K >> 5;
    GSTAGE(0, 0);
    GSTAGE(32, 1);
    int cur = 0;
    for (int ks = 0; ks < nks; ++ks) {
        if (ks + 2 < nks) {
            const int pre = (cur == 0) ? 2 : cur - 1;
            GSTAGE((ks + 2) * 32, pre);
            asm volatile("s_waitcnt vmcnt(8)" ::: "memory");
        } else if (ks + 1 < nks) {
            asm volatile("s_waitcnt vmcnt(4)" ::: "memory");
        } else {
            asm volatile("s_waitcnt vmcnt(0)" ::: "memory");
        }
        __builtin_amdgcn_s_barrier();
        bf16x8 af[4], bfr[4];
#pragma unroll
        for (int i = 0; i < 4; ++i)
            af[i] = *(const bf16x8*)(&As[cur][(wr * 64 + i * 16 + lr) * 32 + lg * 8]);
#pragma unroll
        for (int j = 0; j < 4; ++j)
            bfr[j] = *(const bf16x8*)(&Bs[cur][(wc * 64 + j * 16 + lr) * 32 + lg * 8]);
#pragma unroll
        for (int i = 0; i < 4; ++i)
#pragma unroll
            for (int j = 0; j < 4; ++j)
                acc[i][j] = __builtin_amdgcn_mfma_f32_16x16x32_bf16(af[i], bfr[j],
                                                                    acc[i][j], 0, 0, 0);
        __builtin_amdgcn_s_barrier();
        cur = (cur == 2) ? 0 : cur + 1;
    }
#undef GSTAGE

    auto bsel = [&](int ng) -> float {
        if (EPI != 0) return bias0[ng];
        return (ng < 1024) ? bias0[ng] : (ng < 2048) ? bias1[ng - 1024] : bias2[ng - 2048];
    };

    if (EPI == 0 && (n0 + wc * 64) < 2048) {
        const float C1 = -0.41524101186091903f;  // -log2(10000)/32
        const float inv0 = exp2f((float)lr * C1);
        const float inv1 = exp2f((float)(16 + lr) * C1);
#pragma unroll
        for (int i = 0; i < 4; ++i) {
            int mg = m0 + wr * 64 + i * 16 + lg * 4;
#pragma unroll
            for (int r = 0; r < 4; ++r) {
                int m = mg + r;
                int d = days[m];
                int ad = d < 0 ? -d : d;
                ad = ad > 2047 ? 2047 : ad;
                float pos = (float)ad;
#pragma unroll
                for (int j = 0; j < 2; ++j) {
                    int ng1 = n0 + wc * 64 + j * 16 + lr;
                    int ng2 = ng1 + 32;
                    float x1 = acc[i][j][r] + bsel(ng1);
                    float x2 = acc[i][j + 2][r] + bsel(ng2);
                    float ang = pos * (j ? inv1 : inv0);
                    float sn, cs;
                    __sincosf(ang, &sn, &cs);
                    outB[(size_t)m * N + ng1] = f2bf(x1 * cs - x2 * sn);
                    outB[(size_t)m * N + ng2] = f2bf(x2 * cs + x1 * sn);
                }
            }
        }
    } else {
#pragma unroll
        for (int i = 0; i < 4; ++i) {
            int mg = m0 + wr * 64 + i * 16 + lg * 4;
#pragma unroll
            for (int j = 0; j < 4; ++j) {
                int ng = n0 + wc * 64 + j * 16 + lr;
                float bias = bsel(ng);
#pragma unroll
                for (int r = 0; r < 4; ++r) {
                    float v = acc[i][j][r] + bias;
                    if (EPI == 0)
                        outB[(size_t)(mg + r) * N + ng] = f2bf(v);
                    else
                        outF[(size_t)(mg + r) * N + ng] = v;
                }
            }
        }
    }
}

// ---------------- V transpose: qkv v-region -> Vt[b,h,hd,s] ------------------------
__global__ __launch_bounds__(256) void v_transpose_k(const u16* __restrict__ qkv,
                                                     u16* __restrict__ vt) {
    __shared__ u16 tile[64][66];
    int st = blockIdx.x & 31;
    int bh = blockIdx.x >> 5;
    int b = bh >> 4, h = bh & 15;
    int s0 = st * 64;
    int t = threadIdx.x;
#pragma unroll
    for (int it = 0; it < 16; ++it) {
        int idx = it * 256 + t;
        int sr = idx >> 6, c = idx & 63;
        tile[sr][c] = qkv[(size_t)(b * 2048 + s0 + sr) * 3072 + 2048 + h * 64 + c];
    }
    __syncthreads();
#pragma unroll
    for (int it = 0; it < 16; ++it) {
        int idx = it * 256 + t;
        int hd = idx >> 6, sc = idx & 63;
        vt[((size_t)(bh * 64 + hd)) * 2048 + s0 + sc] = tile[sc][hd];
    }
}

// ---------------- V prefix sums over k-tiles: VPS[bh][t][d], t in [0,32] -----------
__global__ __launch_bounds__(256) void vps_k(const u16* __restrict__ vt,
                                             float* __restrict__ vps) {
    __shared__ float ts[32][32];
    const int bh = blockIdx.x >> 1;
    const int d0 = (blockIdx.x & 1) * 32;
    const int dl = threadIdx.x >> 3;
    const int seg = threadIdx.x & 7;
    const u16* vrow = vt + ((size_t)bh * 64 + d0 + dl) * 2048 + seg * 256;
#pragma unroll
    for (int tt = 0; tt < 4; ++tt) {
        float s = 0.f;
#pragma unroll
        for (int i = 0; i < 8; ++i) {
            bf16x8 v = *(const bf16x8*)(vrow + tt * 64 + i * 8);
#pragma unroll
            for (int e = 0; e < 8; ++e) s += bf2f((u16)v[e]);
        }
        ts[dl][seg * 4 + tt] = s;
    }
    __syncthreads();
    if (threadIdx.x < 32) {
        int d = threadIdx.x;
        float acc = 0.f;
        for (int t = 0; t <= 32; ++t) {
            vps[((size_t)bh * 33 + t) * 64 + d0 + d] = acc;
            if (t < 32) acc += ts[d][t];
        }
    }
}

// ---------------- flash attention v9 -----------------------------------------------
__device__ __forceinline__ void attn_tile(const u16* __restrict__ Ks,
                                          const u16* __restrict__ Vs,
                                          u16* __restrict__ Pw,
                                          const int* __restrict__ dbk,
                                          float dkmax_c, bf16x8 pconst, float pcr,
                                          bf16x8 bq0, bf16x8 bq1, float dq_c, float c1,
                                          int qrel, bool domask,
                                          float& l_part, f32x4* acc, int lr, int lg) {
    if (!domask && __all(dkmax_c - dq_c < -20.0f)) {
        l_part += 16.0f * pcr;
        __builtin_amdgcn_s_setprio(1);
#pragma unroll
        for (int pv = 0; pv < 2; ++pv) {
            int chunk = pv * 4 + lg;
#pragma unroll
            for (int c = 0; c < 4; ++c) {
                const int r3 = c * 16 + lr;
                bf16x8 bv = *(const bf16x8*)(Vs + r3 * 64 + ((chunk ^ (r3 & 7)) << 3));
                acc[c] = __builtin_amdgcn_mfma_f32_16x16x32_bf16(pconst, bv, acc[c], 0, 0, 0);
            }
        }
        __builtin_amdgcn_s_setprio(0);
        return;
    }
    f32x4 st_acc[4];
    __builtin_amdgcn_s_setprio(1);
#pragma unroll
    for (int st = 0; st < 4; ++st) {
        const int r2 = st * 16 + lr;
        const u16* kr = Ks + r2 * 64;
        bf16x8 ka0 = *(const bf16x8*)(kr + ((lg ^ (r2 & 7)) << 3));
        bf16x8 ka1 = *(const bf16x8*)(kr + (((4 + lg) ^ (r2 & 7)) << 3));
        f32x4 t = {};
        t = __builtin_amdgcn_mfma_f32_16x16x32_bf16(ka0, bq0, t, 0, 0, 0);
        t = __builtin_amdgcn_mfma_f32_16x16x32_bf16(ka1, bq1, t, 0, 0, 0);
        st_acc[st] = t;
    }
    __builtin_amdgcn_s_setprio(0);
    const float L2E = 1.4426950408889634f;
    const float POFF = 17.312340490667562f;  // 12*log2(e)
    float p[4][4];
#pragma unroll
    for (int st = 0; st < 4; ++st) {
        int4 dk4 = *(const int4*)(dbk + st * 16 + lg * 4);
#pragma unroll
        for (int r = 0; r < 4; ++r) {
            float dkf = (float)((&dk4.x)[r]);
            float dec = exp2f(__builtin_fmaf(dkf, c1, -dq_c));  // decay/8
            float v = st_acc[st][r] * dec;
            p[st][r] = exp2f(__builtin_fmaf(v, L2E, -POFF));
        }
    }
    if (domask) {
#pragma unroll
        for (int st = 0; st < 4; ++st)
#pragma unroll
            for (int r = 0; r < 4; ++r)
                p[st][r] = (st * 16 + lg * 4 + r <= qrel) ? p[st][r] : 0.f;
    }
#pragma unroll
    for (int st = 0; st < 4; ++st)
#pragma unroll
        for (int r = 0; r < 4; ++r) l_part += p[st][r];
#pragma unroll
    for (int st = 0; st < 4; ++st) {
        unsigned lo, hi;
        asm("v_cvt_pk_bf16_f32 %0, %1, %2" : "=v"(lo) : "v"(p[st][0]), "v"(p[st][1]));
        asm("v_cvt_pk_bf16_f32 %0, %1, %2" : "=v"(hi) : "v"(p[st][2]), "v"(p[st][3]));
        uint2 pk;
        pk.x = lo;
        pk.y = hi;
        int chunk = st * 2 + (lg >> 1);
        int idx = lr * 64 + ((chunk ^ (lr & 7)) << 3) + ((lg & 1) << 2);
        *(uint2*)&Pw[idx] = pk;
    }
    __builtin_amdgcn_s_setprio(1);
#pragma unroll
    for (int pv = 0; pv < 2; ++pv) {
        int chunk = pv * 4 + lg;
        bf16x8 pa = *(const bf16x8*)&Pw[lr * 64 + ((chunk ^ (lr & 7)) << 3)];
#pragma unroll
        for (int c = 0; c < 4; ++c) {
            const int r3 = c * 16 + lr;
            bf16x8 bv = *(const bf16x8*)(Vs + r3 * 64 + ((chunk ^ (r3 & 7)) << 3));
            acc[c] = __builtin_amdgcn_mfma_f32_16x16x32_bf16(pa, bv, acc[c], 0, 0, 0);
        }
    }
    __builtin_amdgcn_s_setprio(0);
}

__global__ __launch_bounds__(256, 4) void attn_k(const u16* __restrict__ qkv,
                                                 const u16* __restrict__ vt,
                                                 const int* __restrict__ days,
                                                 const float* __restrict__ decay_p,
                                                 const float* __restrict__ vps,
                                                 u16* __restrict__ attn_out) {
    __shared__ __align__(16) u16 Ks[2][4096];
    __shared__ __align__(16) u16 Vs[2][4096];
    __shared__ __align__(16) u16 Plds[4][1024];
    const int tid = threadIdx.x;
    const int lane = tid & 63;
    const int w = tid >> 6;
    const int lr = lane & 15, lg = lane >> 4;
    const int wg = (blockIdx.x & 7) * 128 + (blockIdx.x >> 3);
    const int qt = wg & 31;
    const int bh = wg >> 5;
    const int b = bh >> 4, h = bh & 15;
    const int qb = qt * 64 + w * 16;
    const float rate = decay_p[0];
    const float c1 = rate * 1.4426950408889634f;

    const u16* qmat = qkv + (size_t)b * 2048 * 3072 + h * 64;
    const u16* kmat = qmat + 1024;
    const u16* vtm = vt + (size_t)bh * 64 * 2048;
    const int* db = days + b * 2048;

    const int cp0 = (w * 2 + 0) * 64 + lane;
    const int cp1 = (w * 2 + 1) * 64 + lane;
    const int r0 = cp0 >> 3, c0 = cp0 & 7;
    const int r1 = cp1 >> 3, c1i = cp1 & 7;
    const u16* ksrc0 = kmat + (size_t)r0 * 3072 + ((c0 ^ (r0 & 7)) << 3);
    const u16* ksrc1 = kmat + (size_t)r1 * 3072 + ((c1i ^ (r1 & 7)) << 3);
    const u16* vsrc0 = vtm + (size_t)r0 * 2048 + ((c0 ^ (r0 & 7)) << 3);
    const u16* vsrc1 = vtm + (size_t)r1 * 2048 + ((c1i ^ (r1 & 7)) << 3);
    const int doff0 = (w * 2 + 0) * 512;
    const int doff1 = (w * 2 + 1) * 512;

#define STAGE(T, SLOT)                                                                 \
    do {                                                                               \
        __builtin_amdgcn_global_load_lds(                                              \
            (const __attribute__((address_space(1))) void*)(ksrc0 +                    \
                                                            (size_t)(T) * 64 * 3072), \
            (__attribute__((address_space(3))) void*)(&Ks[SLOT][doff0]), 16, 0, 0);    \
        __builtin_amdgcn_global_load_lds(                                              \
            (const __attribute__((address_space(1))) void*)(ksrc1 +                    \
                                                            (size_t)(T) * 64 * 3072), \
            (__attribute__((address_space(3))) void*)(&Ks[SLOT][doff1]), 16, 0, 0);    \
        __builtin_amdgcn_global_load_lds(                                              \
            (const __attribute__((address_space(1))) void*)(vsrc0 + (size_t)(T) * 64), \
            (__attribute__((address_space(3))) void*)(&Vs[SLOT][doff0]), 16, 0, 0);    \
        __builtin_amdgcn_global_load_lds(                                              \
            (const __attribute__((address_space(1))) void*)(vsrc1 + (size_t)(T) * 64), \
            (__attribute__((address_space(3))) void*)(&Vs[SLOT][doff1]), 16, 0, 0);    \
    } while (0)

    const float dq00_c = (float)db[qt * 64] * c1 + 3.0f;
    int t0;
    {
        const int l32 = lane & 31;
        float dm = (float)db[l32 * 64 + 63] * c1;
        bool cnd = (lane < qt) && (dm < dq00_c - 20.0f);
        unsigned long long m = __ballot(cnd);
        t0 = (int)__builtin_ctzll(~m);
    }

    STAGE(t0, 0);

    bf16x8 bq0, bq1;
    {
        const u16* qp = qmat + (size_t)(qb + lr) * 3072 + lg * 8;
        bq0 = *(const bf16x8*)qp;
        bq1 = *(const bf16x8*)(qp + 32);
    }
    const float dq_c = (float)db[qb + lr] * c1 + 3.0f;

    const u16 pcu = f2bf(exp2f(-17.312340490667562f));
    const float pcr = bf2f(pcu);
    bf16x8 pconst;
#pragma unroll
    for (int i = 0; i < 8; ++i) pconst[i] = (short)pcu;

    float lp = (float)t0 * 16.0f * pcr;
    f32x4 acc[4];
#pragma unroll
    for (int c = 0; c < 4; ++c) {
        float vv = pcr * vps[((size_t)bh * 33 + t0) * 64 + c * 16 + lr];
        acc[c] = (f32x4){vv, vv, vv, vv};
    }

    for (int kt = t0; kt <= qt; ++kt) {
        const int cur = (kt - t0) & 1;
        if (kt < qt) {
            STAGE(kt + 1, cur ^ 1);
            asm volatile("s_waitcnt vmcnt(4)" ::: "memory");
        } else {
            asm volatile("s_waitcnt vmcnt(0)" ::: "memory");
        }
        __builtin_amdgcn_s_barrier();
        const int* dbk = db + kt * 64;
        const float dkmax_c = (float)dbk[63] * c1;
        attn_tile(Ks[cur], Vs[cur], Plds[w], dbk, dkmax_c, pconst, pcr,
                  bq0, bq1, dq_c, c1, w * 16 + lr, kt == qt, lp, acc, lr, lg);
        __builtin_amdgcn_s_barrier();
    }
#undef STAGE

    float l_full = lp + __shfl_xor(lp, 16);
    l_full += __shfl_xor(l_full, 32);
    float inv_[4];
#pragma unroll
    for (int r = 0; r < 4; ++r) inv_[r] = 1.0f / __shfl(l_full, lg * 4 + r);
#pragma unroll
    for (int c = 0; c < 4; ++c)
#pragma unroll
        for (int r = 0; r < 4; ++r) {
            const int qg = qb + lg * 4 + r;
            attn_out[(size_t)(b * 2048 + qg) * 1024 + h * 64 + c * 16 + lr] =
                f2bf(acc[c][r] * inv_[r]);
        }
}

// ---------------- launch -----------------------------------------------------------
extern "C" void kernel_launch(void* const* d_in, const int* in_sizes, int n_in,
                              void* d_out, int out_size, void* d_ws, size_t ws_size,
                              hipStream_t stream) {
    const float* x = (const float*)d_in[0];
    const float* Wq = (const float*)d_in[1];
    const float* bq = (const float*)d_in[2];
    const float* Wk = (const float*)d_in[3];
    const float* bk = (const float*)d_in[4];
    const float* Wv = (const float*)d_in[5];
    const float* bv = (const float*)d_in[6];
    const float* Wo = (const float*)d_in[7];
    const float* bo = (const float*)d_in[8];
    const float* decay = (const float*)d_in[9];
    const int* days = (const int*)d_in[11];
    float* out = (float*)d_out;

    char* ws = (char*)d_ws;
    u16* xb = (u16*)(ws);                   //  8 MB: x bf16 [4096][1024]
    u16* wqkv = (u16*)(ws + 8388608);       //  6 MB: [Wq;Wk;Wv] bf16 [3072][1024]
    u16* wo = (u16*)(ws + 14680064);        //  2 MB: Wo bf16 [1024][1024]
    u16* qkvb = (u16*)(ws + 16777216);      // 24 MB: qkv bf16 [4096][3072]
    u16* vtb = (u16*)(ws + 41943040);       //  8 MB: Vt bf16 [32][64][2048]
    u16* attb = (u16*)(ws + 50331648);      //  8 MB: attn out bf16 [4096][1024]
    float* vpsb = (float*)(ws + 58720256);  // 270 KB: V prefix sums [32][33][64] f32

    convert_all_k<<<8192, 256, 0, stream>>>(x, Wq, Wk, Wv, Wo, xb, wqkv, wo);

    gemm_bt<0><<<768, 256, 0, stream>>>(xb, wqkv, bq, bk, bv, days, qkvb, nullptr,
                                        4096, 3072, 1024);
    v_transpose_k<<<1024, 256, 0, stream>>>(qkvb, vtb);
    vps_k<<<64, 256, 0, stream>>>(vtb, vpsb);
    attn_k<<<1024, 256, 0, stream>>>(qkvb, vtb, days, decay, vpsb, attb);
    gemm_bt<1><<<256, 256, 0, stream>>>(attb, wo, bo, nullptr, nullptr, days, nullptr,
                                        out, 4096, 1024, 1024);
}

// Round 17
// 101.465 us; speedup vs baseline: 1.6928x; 1.0333x over previous
//
#include <hip/hip_runtime.h>
#include <hip/hip_bf16.h>

// B=2, S=2048, D=1024, H=16, HD=64. fp32 in, fp32 out, bf16-tolerance threshold.
// Pipeline: convert->bf16 | QKV GEMM (fused bias+RoPE; V written transposed to Vt;
//           q|k stored [4096][2048]) | V-prefix-sum | flash attn v9 (far via VPS) |
//           out GEMM (split-K, 2 wave-groups).

typedef unsigned short u16;
typedef short bf16x8 __attribute__((ext_vector_type(8)));
typedef float f32x4 __attribute__((ext_vector_type(4)));

__device__ __forceinline__ u16 f2bf(float f) {
    unsigned u = __builtin_bit_cast(unsigned, f);
    u += 0x7fffu + ((u >> 16) & 1u);   // RNE
    return (u16)(u >> 16);
}
__device__ __forceinline__ float bf2f(u16 h) {
    unsigned u = ((unsigned)h) << 16;
    return __builtin_bit_cast(float, u);
}

// ---------------- fused fp32 -> bf16 convert for all 5 tensors ---------------------
__global__ __launch_bounds__(256) void convert_all_k(const float* __restrict__ x,
                                                     const float* __restrict__ wq,
                                                     const float* __restrict__ wk,
                                                     const float* __restrict__ wv,
                                                     const float* __restrict__ wo_,
                                                     u16* __restrict__ xb,
                                                     u16* __restrict__ wqkv,
                                                     u16* __restrict__ wob) {
    int i = (blockIdx.x * 256 + threadIdx.x) * 4;
    const float* src;
    u16* dst;
    int off;
    if (i < 4194304) {
        src = x; dst = xb; off = i;
    } else if (i < 5242880) {
        src = wq; dst = wqkv; off = i - 4194304;
    } else if (i < 6291456) {
        src = wk; dst = wqkv + 1048576; off = i - 5242880;
    } else if (i < 7340032) {
        src = wv; dst = wqkv + 2097152; off = i - 6291456;
    } else {
        src = wo_; dst = wob; off = i - 7340032;
    }
    float4 v = *(const float4*)(src + off);
    uint2 o;
    o.x = (unsigned)f2bf(v.x) | ((unsigned)f2bf(v.y) << 16);
    o.y = (unsigned)f2bf(v.z) | ((unsigned)f2bf(v.w) << 16);
    *(uint2*)(dst + off) = o;
}

// ---------------- QKV GEMM: C[m][n] = sum_k A[m][k]*Bw[n][k] -----------------------
// Double-buffered LDS, counted vmcnt. Epilogue: cols<2048 -> bias+RoPE -> qk buffer
// (row stride 2048); cols>=2048 (V region) -> bias -> TRANSPOSED write to
// vt[bh][hd][s] (r-packed 8B stores).
__global__ __launch_bounds__(256) void gemm_qkv(const u16* __restrict__ A,
                                                const u16* __restrict__ Bw,
                                                const float* __restrict__ bias0,
                                                const float* __restrict__ bias1,
                                                const float* __restrict__ bias2,
                                                const int* __restrict__ days,
                                                u16* __restrict__ outB,
                                                u16* __restrict__ vt,
                                                int M, int N, int K) {
    __shared__ __align__(16) u16 As[2][4096];
    __shared__ __align__(16) u16 Bs[2][4096];
    const int tid = threadIdx.x;
    const int lane = tid & 63;
    const int w = tid >> 6;
    const int wr = w >> 1, wc = w & 1;
    const int lr = lane & 15, lg = lane >> 4;
    const int nbn = N >> 7;
    const int m0 = (blockIdx.x / nbn) << 7;
    const int n0 = (blockIdx.x % nbn) << 7;

    f32x4 acc[4][4] = {};

    const u16* aptr[2];
    const u16* bptr[2];
    int ldsoff[2];
#pragma unroll
    for (int i = 0; i < 2; ++i) {
        int c = (w * 2 + i) * 64 + lane;
        int row = c >> 2, kc = (c & 3) << 3;
        aptr[i] = A + (size_t)(m0 + row) * K + kc;
        bptr[i] = Bw + (size_t)(n0 + row) * K + kc;
        ldsoff[i] = (w * 2 + i) * 512;
    }

#define GSTAGE(K0, BUF)                                                                \
    do {                                                                               \
        _Pragma("unroll") for (int i = 0; i < 2; ++i) {                                \
            __builtin_amdgcn_global_load_lds(                                          \
                (const __attribute__((address_space(1))) void*)(aptr[i] + (K0)),       \
                (__attribute__((address_space(3))) void*)(&As[BUF][ldsoff[i]]), 16, 0, \
                0);                                                                    \
            __builtin_amdgcn_global_load_lds(                                          \
                (const __attribute__((address_space(1))) void*)(bptr[i] + (K0)),       \
                (__attribute__((address_space(3))) void*)(&Bs[BUF][ldsoff[i]]), 16, 0, \
                0);                                                                    \
        }                                                                              \
    } while (0)

    const int nks = K >> 5;
    GSTAGE(0, 0);
    for (int ks = 0; ks < nks; ++ks) {
        const int cur = ks & 1;
        if (ks + 1 < nks) {
            GSTAGE((ks + 1) * 32, cur ^ 1);
            asm volatile("s_waitcnt vmcnt(4)" ::: "memory");
        } else {
            asm volatile("s_waitcnt vmcnt(0)" ::: "memory");
        }
        __builtin_amdgcn_s_barrier();
        bf16x8 af[4], bfr[4];
#pragma unroll
        for (int i = 0; i < 4; ++i)
            af[i] = *(const bf16x8*)(&As[cur][(wr * 64 + i * 16 + lr) * 32 + lg * 8]);
#pragma unroll
        for (int j = 0; j < 4; ++j)
            bfr[j] = *(const bf16x8*)(&Bs[cur][(wc * 64 + j * 16 + lr) * 32 + lg * 8]);
#pragma unroll
        for (int i = 0; i < 4; ++i)
#pragma unroll
            for (int j = 0; j < 4; ++j)
                acc[i][j] = __builtin_amdgcn_mfma_f32_16x16x32_bf16(af[i], bfr[j],
                                                                    acc[i][j], 0, 0, 0);
        __builtin_amdgcn_s_barrier();
    }
#undef GSTAGE

    auto bsel = [&](int ng) -> float {
        return (ng < 1024) ? bias0[ng] : (ng < 2048) ? bias1[ng - 1024] : bias2[ng - 2048];
    };

    if ((n0 + wc * 64) < 2048) {
        // q/k region: wave's 64 cols = one full head; pairs (j, j+2) hold (x1, x2).
        const float C1 = -0.41524101186091903f;  // -log2(10000)/32
        const float inv0 = exp2f((float)lr * C1);
        const float inv1 = exp2f((float)(16 + lr) * C1);
#pragma unroll
        for (int i = 0; i < 4; ++i) {
            int mg = m0 + wr * 64 + i * 16 + lg * 4;
#pragma unroll
            for (int r = 0; r < 4; ++r) {
                int m = mg + r;
                int d = days[m];
                int ad = d < 0 ? -d : d;
                ad = ad > 2047 ? 2047 : ad;
                float pos = (float)ad;
#pragma unroll
                for (int j = 0; j < 2; ++j) {
                    int ng1 = n0 + wc * 64 + j * 16 + lr;
                    int ng2 = ng1 + 32;
                    float x1 = acc[i][j][r] + bsel(ng1);
                    float x2 = acc[i][j + 2][r] + bsel(ng2);
                    float ang = pos * (j ? inv1 : inv0);
                    float sn, cs;
                    __sincosf(ang, &sn, &cs);
                    outB[(size_t)m * 2048 + ng1] = f2bf(x1 * cs - x2 * sn);
                    outB[(size_t)m * 2048 + ng2] = f2bf(x2 * cs + x1 * sn);
                }
            }
        }
    } else {
        // V region: write transposed into vt[bh][hd][s]; 4 consecutive s packed 8B.
        const int h = ((n0 + wc * 64) - 2048) >> 6;
#pragma unroll
        for (int i = 0; i < 4; ++i) {
            int mg = m0 + wr * 64 + i * 16 + lg * 4;
            int b = mg >> 11, s0 = mg & 2047;
#pragma unroll
            for (int j = 0; j < 4; ++j) {
                int hd = j * 16 + lr;
                int ng = 2048 + h * 64 + hd;
                float bias = bsel(ng);
                ushort4 o;
                o.x = f2bf(acc[i][j][0] + bias);
                o.y = f2bf(acc[i][j][1] + bias);
                o.z = f2bf(acc[i][j][2] + bias);
                o.w = f2bf(acc[i][j][3] + bias);
                *(ushort4*)&vt[((size_t)(b * 16 + h) * 64 + hd) * 2048 + s0] = o;
            }
        }
    }
}

// ---------------- out-proj GEMM: split-K across 2 wave-groups ----------------------
// 512 threads; group g computes K[g*512, g*512+512) into fp32 acc; partials merged
// through LDS; group 0 adds bias and writes fp32 out. M=4096, N=1024, K=1024.
__global__ __launch_bounds__(512, 2) void gemm_out(const u16* __restrict__ A,
                                                   const u16* __restrict__ Bw,
                                                   const float* __restrict__ bias0,
                                                   float* __restrict__ outF,
                                                   int M, int N, int K) {
    __shared__ __align__(16) u16 As[2][2][4096];  // [group][buf]
    __shared__ __align__(16) u16 Bs[2][2][4096];
    const int tid = threadIdx.x;
    const int lane = tid & 63;
    const int w4 = (tid >> 6) & 3;
    const int g = tid >> 8;
    const int wr = w4 >> 1, wc = w4 & 1;
    const int lr = lane & 15, lg = lane >> 4;
    const int nbn = N >> 7;
    const int m0 = (blockIdx.x / nbn) << 7;
    const int n0 = (blockIdx.x % nbn) << 7;
    const int kbase = g * (K >> 1);

    f32x4 acc[4][4] = {};

    const u16* aptr[2];
    const u16* bptr[2];
    int ldsoff[2];
#pragma unroll
    for (int i = 0; i < 2; ++i) {
        int c = (w4 * 2 + i) * 64 + lane;
        int row = c >> 2, kc = (c & 3) << 3;
        aptr[i] = A + (size_t)(m0 + row) * K + kbase + kc;
        bptr[i] = Bw + (size_t)(n0 + row) * K + kbase + kc;
        ldsoff[i] = (w4 * 2 + i) * 512;
    }

#define GSTAGE(K0, BUF)                                                                \
    do {                                                                               \
        _Pragma("unroll") for (int i = 0; i < 2; ++i) {                                \
            __builtin_amdgcn_global_load_lds(                                          \
                (const __attribute__((address_space(1))) void*)(aptr[i] + (K0)),       \
                (__attribute__((address_space(3))) void*)(&As[g][BUF][ldsoff[i]]), 16, \
                0, 0);                                                                 \
            __builtin_amdgcn_global_load_lds(                                          \
                (const __attribute__((address_space(1))) void*)(bptr[i] + (K0)),       \
                (__attribute__((address_space(3))) void*)(&Bs[g][BUF][ldsoff[i]]), 16, \
                0, 0);                                                                 \
        }                                                                              \
    } while (0)

    const int nks = K >> 6;  // per-group steps = K/2/32 = 16
    GSTAGE(0, 0);
    for (int ks = 0; ks < nks; ++ks) {
        const int cur = ks & 1;
        if (ks + 1 < nks) {
            GSTAGE((ks + 1) * 32, cur ^ 1);
            asm volatile("s_waitcnt vmcnt(4)" ::: "memory");
        } else {
            asm volatile("s_waitcnt vmcnt(0)" ::: "memory");
        }
        __builtin_amdgcn_s_barrier();
        bf16x8 af[4], bfr[4];
#pragma unroll
        for (int i = 0; i < 4; ++i)
            af[i] = *(const bf16x8*)(&As[g][cur][(wr * 64 + i * 16 + lr) * 32 + lg * 8]);
#pragma unroll
        for (int j = 0; j < 4; ++j)
            bfr[j] = *(const bf16x8*)(&Bs[g][cur][(wc * 64 + j * 16 + lr) * 32 + lg * 8]);
#pragma unroll
        for (int i = 0; i < 4; ++i)
#pragma unroll
            for (int j = 0; j < 4; ++j)
                acc[i][j] = __builtin_amdgcn_mfma_f32_16x16x32_bf16(af[i], bfr[j],
                                                                    acc[i][j], 0, 0, 0);
        __builtin_amdgcn_s_barrier();
    }
#undef GSTAGE

    // merge group partials through LDS in 2 chunks of 32KB (reuse As+Bs storage)
    float* xch = (float*)&As[0][0][0];
    const int t256 = tid & 255;
#pragma unroll
    for (int hf = 0; hf < 2; ++hf) {
        __syncthreads();
        if (g == 1) {
#pragma unroll
            for (int i = 0; i < 2; ++i)
#pragma unroll
                for (int j = 0; j < 4; ++j)
                    *(f32x4*)&xch[((t256 * 8) + i * 4 + j) * 4] = acc[hf * 2 + i][j];
        }
        __syncthreads();
        if (g == 0) {
#pragma unroll
            for (int i = 0; i < 2; ++i)
#pragma unroll
                for (int j = 0; j < 4; ++j)
                    acc[hf * 2 + i][j] += *(const f32x4*)&xch[((t256 * 8) + i * 4 + j) * 4];
        }
    }
    if (g == 0) {
#pragma unroll
        for (int i = 0; i < 4; ++i) {
            int mg = m0 + wr * 64 + i * 16 + lg * 4;
#pragma unroll
            for (int j = 0; j < 4; ++j) {
                int ng = n0 + wc * 64 + j * 16 + lr;
                float bias = bias0[ng];
#pragma unroll
                for (int r = 0; r < 4; ++r)
                    outF[(size_t)(mg + r) * N + ng] = acc[i][j][r] + bias;
            }
        }
    }
}

// ---------------- V prefix sums over k-tiles: VPS[bh][t][d], t in [0,32] -----------
__global__ __launch_bounds__(256) void vps_k(const u16* __restrict__ vt,
                                             float* __restrict__ vps) {
    __shared__ float ts[32][32];
    const int bh = blockIdx.x >> 1;
    const int d0 = (blockIdx.x & 1) * 32;
    const int dl = threadIdx.x >> 3;
    const int seg = threadIdx.x & 7;
    const u16* vrow = vt + ((size_t)bh * 64 + d0 + dl) * 2048 + seg * 256;
#pragma unroll
    for (int tt = 0; tt < 4; ++tt) {
        float s = 0.f;
#pragma unroll
        for (int i = 0; i < 8; ++i) {
            bf16x8 v = *(const bf16x8*)(vrow + tt * 64 + i * 8);
#pragma unroll
            for (int e = 0; e < 8; ++e) s += bf2f((u16)v[e]);
        }
        ts[dl][seg * 4 + tt] = s;
    }
    __syncthreads();
    if (threadIdx.x < 32) {
        int d = threadIdx.x;
        float acc = 0.f;
        for (int t = 0; t <= 32; ++t) {
            vps[((size_t)bh * 33 + t) * 64 + d0 + d] = acc;
            if (t < 32) acc += ts[d][t];
        }
    }
}

// ---------------- flash attention v9 -----------------------------------------------
__device__ __forceinline__ void attn_tile(const u16* __restrict__ Ks,
                                          const u16* __restrict__ Vs,
                                          u16* __restrict__ Pw,
                                          const int* __restrict__ dbk,
                                          float dkmax_c, bf16x8 pconst, float pcr,
                                          bf16x8 bq0, bf16x8 bq1, float dq_c, float c1,
                                          int qrel, bool domask,
                                          float& l_part, f32x4* acc, int lr, int lg) {
    if (!domask && __all(dkmax_c - dq_c < -20.0f)) {
        l_part += 16.0f * pcr;
        __builtin_amdgcn_s_setprio(1);
#pragma unroll
        for (int pv = 0; pv < 2; ++pv) {
            int chunk = pv * 4 + lg;
#pragma unroll
            for (int c = 0; c < 4; ++c) {
                const int r3 = c * 16 + lr;
                bf16x8 bv = *(const bf16x8*)(Vs + r3 * 64 + ((chunk ^ (r3 & 7)) << 3));
                acc[c] = __builtin_amdgcn_mfma_f32_16x16x32_bf16(pconst, bv, acc[c], 0, 0, 0);
            }
        }
        __builtin_amdgcn_s_setprio(0);
        return;
    }
    f32x4 st_acc[4];
    __builtin_amdgcn_s_setprio(1);
#pragma unroll
    for (int st = 0; st < 4; ++st) {
        const int r2 = st * 16 + lr;
        const u16* kr = Ks + r2 * 64;
        bf16x8 ka0 = *(const bf16x8*)(kr + ((lg ^ (r2 & 7)) << 3));
        bf16x8 ka1 = *(const bf16x8*)(kr + (((4 + lg) ^ (r2 & 7)) << 3));
        f32x4 t = {};
        t = __builtin_amdgcn_mfma_f32_16x16x32_bf16(ka0, bq0, t, 0, 0, 0);
        t = __builtin_amdgcn_mfma_f32_16x16x32_bf16(ka1, bq1, t, 0, 0, 0);
        st_acc[st] = t;
    }
    __builtin_amdgcn_s_setprio(0);
    const float L2E = 1.4426950408889634f;
    const float POFF = 17.312340490667562f;  // 12*log2(e)
    float p[4][4];
#pragma unroll
    for (int st = 0; st < 4; ++st) {
        int4 dk4 = *(const int4*)(dbk + st * 16 + lg * 4);
#pragma unroll
        for (int r = 0; r < 4; ++r) {
            float dkf = (float)((&dk4.x)[r]);
            float dec = exp2f(__builtin_fmaf(dkf, c1, -dq_c));  // decay/8
            float v = st_acc[st][r] * dec;
            p[st][r] = exp2f(__builtin_fmaf(v, L2E, -POFF));
        }
    }
    if (domask) {
#pragma unroll
        for (int st = 0; st < 4; ++st)
#pragma unroll
            for (int r = 0; r < 4; ++r)
                p[st][r] = (st * 16 + lg * 4 + r <= qrel) ? p[st][r] : 0.f;
    }
#pragma unroll
    for (int st = 0; st < 4; ++st)
#pragma unroll
        for (int r = 0; r < 4; ++r) l_part += p[st][r];
#pragma unroll
    for (int st = 0; st < 4; ++st) {
        unsigned lo, hi;
        asm("v_cvt_pk_bf16_f32 %0, %1, %2" : "=v"(lo) : "v"(p[st][0]), "v"(p[st][1]));
        asm("v_cvt_pk_bf16_f32 %0, %1, %2" : "=v"(hi) : "v"(p[st][2]), "v"(p[st][3]));
        uint2 pk;
        pk.x = lo;
        pk.y = hi;
        int chunk = st * 2 + (lg >> 1);
        int idx = lr * 64 + ((chunk ^ (lr & 7)) << 3) + ((lg & 1) << 2);
        *(uint2*)&Pw[idx] = pk;
    }
    __builtin_amdgcn_s_setprio(1);
#pragma unroll
    for (int pv = 0; pv < 2; ++pv) {
        int chunk = pv * 4 + lg;
        bf16x8 pa = *(const bf16x8*)&Pw[lr * 64 + ((chunk ^ (lr & 7)) << 3)];
#pragma unroll
        for (int c = 0; c < 4; ++c) {
            const int r3 = c * 16 + lr;
            bf16x8 bv = *(const bf16x8*)(Vs + r3 * 64 + ((chunk ^ (r3 & 7)) << 3));
            acc[c] = __builtin_amdgcn_mfma_f32_16x16x32_bf16(pa, bv, acc[c], 0, 0, 0);
        }
    }
    __builtin_amdgcn_s_setprio(0);
}

__global__ __launch_bounds__(256, 4) void attn_k(const u16* __restrict__ qkv,
                                                 const u16* __restrict__ vt,
                                                 const int* __restrict__ days,
                                                 const float* __restrict__ decay_p,
                                                 const float* __restrict__ vps,
                                                 u16* __restrict__ attn_out) {
    __shared__ __align__(16) u16 Ks[2][4096];
    __shared__ __align__(16) u16 Vs[2][4096];
    __shared__ __align__(16) u16 Plds[4][1024];
    const int tid = threadIdx.x;
    const int lane = tid & 63;
    const int w = tid >> 6;
    const int lr = lane & 15, lg = lane >> 4;
    const int wg = (blockIdx.x & 7) * 128 + (blockIdx.x >> 3);
    const int qt = wg & 31;
    const int bh = wg >> 5;
    const int b = bh >> 4, h = bh & 15;
    const int qb = qt * 64 + w * 16;
    const float rate = decay_p[0];
    const float c1 = rate * 1.4426950408889634f;

    // q|k buffer: rows [4096], stride 2048 (q cols 0..1023, k cols 1024..2047)
    const u16* qmat = qkv + (size_t)b * 2048 * 2048 + h * 64;
    const u16* kmat = qmat + 1024;
    const u16* vtm = vt + (size_t)bh * 64 * 2048;
    const int* db = days + b * 2048;

    const int cp0 = (w * 2 + 0) * 64 + lane;
    const int cp1 = (w * 2 + 1) * 64 + lane;
    const int r0 = cp0 >> 3, c0 = cp0 & 7;
    const int r1 = cp1 >> 3, c1i = cp1 & 7;
    const u16* ksrc0 = kmat + (size_t)r0 * 2048 + ((c0 ^ (r0 & 7)) << 3);
    const u16* ksrc1 = kmat + (size_t)r1 * 2048 + ((c1i ^ (r1 & 7)) << 3);
    const u16* vsrc0 = vtm + (size_t)r0 * 2048 + ((c0 ^ (r0 & 7)) << 3);
    const u16* vsrc1 = vtm + (size_t)r1 * 2048 + ((c1i ^ (r1 & 7)) << 3);
    const int doff0 = (w * 2 + 0) * 512;
    const int doff1 = (w * 2 + 1) * 512;

#define STAGE(T, SLOT)                                                                 \
    do {                                                                               \
        __builtin_amdgcn_global_load_lds(                                              \
            (const __attribute__((address_space(1))) void*)(ksrc0 +                    \
                                                            (size_t)(T) * 64 * 2048), \
            (__attribute__((address_space(3))) void*)(&Ks[SLOT][doff0]), 16, 0, 0);    \
        __builtin_amdgcn_global_load_lds(                                              \
            (const __attribute__((address_space(1))) void*)(ksrc1 +                    \
                                                            (size_t)(T) * 64 * 2048), \
            (__attribute__((address_space(3))) void*)(&Ks[SLOT][doff1]), 16, 0, 0);    \
        __builtin_amdgcn_global_load_lds(                                              \
            (const __attribute__((address_space(1))) void*)(vsrc0 + (size_t)(T) * 64), \
            (__attribute__((address_space(3))) void*)(&Vs[SLOT][doff0]), 16, 0, 0);    \
        __builtin_amdgcn_global_load_lds(                                              \
            (const __attribute__((address_space(1))) void*)(vsrc1 + (size_t)(T) * 64), \
            (__attribute__((address_space(3))) void*)(&Vs[SLOT][doff1]), 16, 0, 0);    \
    } while (0)

    const float dq00_c = (float)db[qt * 64] * c1 + 3.0f;
    int t0;
    {
        const int l32 = lane & 31;
        float dm = (float)db[l32 * 64 + 63] * c1;
        bool cnd = (lane < qt) && (dm < dq00_c - 20.0f);
        unsigned long long m = __ballot(cnd);
        t0 = (int)__builtin_ctzll(~m);
    }

    STAGE(t0, 0);

    bf16x8 bq0, bq1;
    {
        const u16* qp = qmat + (size_t)(qb + lr) * 2048 + lg * 8;
        bq0 = *(const bf16x8*)qp;
        bq1 = *(const bf16x8*)(qp + 32);
    }
    const float dq_c = (float)db[qb + lr] * c1 + 3.0f;

    const u16 pcu = f2bf(exp2f(-17.312340490667562f));
    const float pcr = bf2f(pcu);
    bf16x8 pconst;
#pragma unroll
    for (int i = 0; i < 8; ++i) pconst[i] = (short)pcu;

    float lp = (float)t0 * 16.0f * pcr;
    f32x4 acc[4];
#pragma unroll
    for (int c = 0; c < 4; ++c) {
        float vv = pcr * vps[((size_t)bh * 33 + t0) * 64 + c * 16 + lr];
        acc[c] = (f32x4){vv, vv, vv, vv};
    }

    for (int kt = t0; kt <= qt; ++kt) {
        const int cur = (kt - t0) & 1;
        if (kt < qt) {
            STAGE(kt + 1, cur ^ 1);
            asm volatile("s_waitcnt vmcnt(4)" ::: "memory");
        } else {
            asm volatile("s_waitcnt vmcnt(0)" ::: "memory");
        }
        __builtin_amdgcn_s_barrier();
        const int* dbk = db + kt * 64;
        const float dkmax_c = (float)dbk[63] * c1;
        attn_tile(Ks[cur], Vs[cur], Plds[w], dbk, dkmax_c, pconst, pcr,
                  bq0, bq1, dq_c, c1, w * 16 + lr, kt == qt, lp, acc, lr, lg);
        __builtin_amdgcn_s_barrier();
    }
#undef STAGE

    float l_full = lp + __shfl_xor(lp, 16);
    l_full += __shfl_xor(l_full, 32);
    float inv_[4];
#pragma unroll
    for (int r = 0; r < 4; ++r) inv_[r] = 1.0f / __shfl(l_full, lg * 4 + r);
#pragma unroll
    for (int c = 0; c < 4; ++c)
#pragma unroll
        for (int r = 0; r < 4; ++r) {
            const int qg = qb + lg * 4 + r;
            attn_out[(size_t)(b * 2048 + qg) * 1024 + h * 64 + c * 16 + lr] =
                f2bf(acc[c][r] * inv_[r]);
        }
}

// ---------------- launch -----------------------------------------------------------
extern "C" void kernel_launch(void* const* d_in, const int* in_sizes, int n_in,
                              void* d_out, int out_size, void* d_ws, size_t ws_size,
                              hipStream_t stream) {
    const float* x = (const float*)d_in[0];
    const float* Wq = (const float*)d_in[1];
    const float* bq = (const float*)d_in[2];
    const float* Wk = (const float*)d_in[3];
    const float* bk = (const float*)d_in[4];
    const float* Wv = (const float*)d_in[5];
    const float* bv = (const float*)d_in[6];
    const float* Wo = (const float*)d_in[7];
    const float* bo = (const float*)d_in[8];
    const float* decay = (const float*)d_in[9];
    const int* days = (const int*)d_in[11];
    float* out = (float*)d_out;

    char* ws = (char*)d_ws;
    u16* xb = (u16*)(ws);                   //  8 MB: x bf16 [4096][1024]
    u16* wqkv = (u16*)(ws + 8388608);       //  6 MB: [Wq;Wk;Wv] bf16 [3072][1024]
    u16* wo = (u16*)(ws + 14680064);        //  2 MB: Wo bf16 [1024][1024]
    u16* qkb = (u16*)(ws + 16777216);       // 16 MB: q|k bf16 [4096][2048]
    u16* vtb = (u16*)(ws + 41943040);       //  8 MB: Vt bf16 [32][64][2048]
    u16* attb = (u16*)(ws + 50331648);      //  8 MB: attn out bf16 [4096][1024]
    float* vpsb = (float*)(ws + 58720256);  // 270 KB: V prefix sums [32][33][64] f32

    convert_all_k<<<8192, 256, 0, stream>>>(x, Wq, Wk, Wv, Wo, xb, wqkv, wo);

    gemm_qkv<<<768, 256, 0, stream>>>(xb, wqkv, bq, bk, bv, days, qkb, vtb, 4096,
                                      3072, 1024);
    vps_k<<<64, 256, 0, stream>>>(vtb, vpsb);
    attn_k<<<1024, 256, 0, stream>>>(qkb, vtb, days, decay, vpsb, attb);
    gemm_out<<<256, 512, 0, stream>>>(attb, wo, bo, out, 4096, 1024, 1024);
}